// Round 12
// baseline (1763.204 us; speedup 1.0000x reference)
//
#include <hip/hip_runtime.h>
#include <hip/hip_bf16.h>
#include <math.h>

#define B_ 16
#define S_ 256
#define T_ 800
#define V_ 256
#define D_ 512
#define M_ 80
#define H_ 1024
#define NH_ 4
#define HD_ 128
#define EH_ 256

using bf16x8 = __attribute__((ext_vector_type(8))) short;
using f32x4  = __attribute__((ext_vector_type(4))) float;
typedef _Float16 half8 __attribute__((ext_vector_type(8)));

__device__ __forceinline__ float sigf(float x) { return 1.f / (1.f + __expf(-x)); }
__device__ __forceinline__ float tanhfast(float x) {
    float e = __expf(2.f * x);
    return 1.f - 2.f / (e + 1.f);
}

__device__ __forceinline__ unsigned short f2bf(float f) {
    unsigned int u = __float_as_uint(f);
    unsigned int r = (u + 0x7FFFu + ((u >> 16) & 1u)) >> 16;
    return (unsigned short)r;
}
__device__ __forceinline__ float bf2f(unsigned short u) {
    return __uint_as_float(((unsigned int)u) << 16);
}
__device__ __forceinline__ unsigned short h2u(_Float16 x) {
    union { _Float16 f; unsigned short u; } c; c.f = x; return c.u;
}

__device__ __forceinline__ void gl_lds16(const unsigned short* g, unsigned short* l) {
    __builtin_amdgcn_global_load_lds((const __attribute__((address_space(1))) void*)g,
                                     (__attribute__((address_space(3))) void*)l, 16, 0, 0);
}

// ---------------- MFMA bf16 GEMM: C = A(M,K) @ B(N,K)^T --------------------
// epi: 0 fp32(+bias), 1 conv BN+ReLU fp32, 2 bf16(+bias), 3 v^T bf16, 4 fp32 col<80
__global__ __launch_bounds__(256) void gemm_mfma(
    const unsigned short* __restrict__ A, const unsigned short* __restrict__ Bw,
    void* __restrict__ Cv, const float* __restrict__ bias,
    int M, int N, int K, int ldc, int epi,
    const float* __restrict__ cb, const float* __restrict__ gam,
    const float* __restrict__ bet, const float* __restrict__ mu,
    const float* __restrict__ va)
{
    __shared__ unsigned short As[4096];
    __shared__ unsigned short Bs[4096];
    const int tid = threadIdx.x, w = tid >> 6, lane = tid & 63;
    const int bm = blockIdx.y * 128, bn = blockIdx.x * 128;
    const int wr = w >> 1, wc = w & 1;

    f32x4 acc[4][4];
#pragma unroll
    for (int m = 0; m < 4; ++m)
#pragma unroll
        for (int n = 0; n < 4; ++n) acc[m][n] = (f32x4){0.f, 0.f, 0.f, 0.f};

    const int r0 = w * 16 + (lane >> 2);
    const int k8 = (lane & 3) * 8;
    const unsigned short* Ag = A + (size_t)(bm + r0) * K + k8;
    const unsigned short* Bg = Bw + (size_t)(bn + r0) * K + k8;
    unsigned short* Al = As + w * 512;
    unsigned short* Bl = Bs + w * 512;

    for (int k0 = 0; k0 < K; k0 += 32) {
        __syncthreads();
        gl_lds16(Ag + k0, Al);
        gl_lds16(Ag + (size_t)64 * K + k0, Al + 2048);
        gl_lds16(Bg + k0, Bl);
        gl_lds16(Bg + (size_t)64 * K + k0, Bl + 2048);
        __syncthreads();
        bf16x8 a[4], b[4];
#pragma unroll
        for (int m = 0; m < 4; ++m)
            a[m] = *(const bf16x8*)(As + (wr * 64 + m * 16 + (lane & 15)) * 32 + (lane >> 4) * 8);
#pragma unroll
        for (int n = 0; n < 4; ++n)
            b[n] = *(const bf16x8*)(Bs + (wc * 64 + n * 16 + (lane & 15)) * 32 + (lane >> 4) * 8);
#pragma unroll
        for (int m = 0; m < 4; ++m)
#pragma unroll
            for (int n = 0; n < 4; ++n)
                acc[m][n] = __builtin_amdgcn_mfma_f32_16x16x32_bf16(a[m], b[n], acc[m][n], 0, 0, 0);
    }

    const int cr = (lane >> 4) * 4, ccol = lane & 15;
#pragma unroll
    for (int m = 0; m < 4; ++m)
#pragma unroll
        for (int n = 0; n < 4; ++n) {
            const int col = bn + wc * 64 + n * 16 + ccol;
            const float bv = (bias && !(epi == 4 && col >= 80)) ? bias[col] : 0.f;
#pragma unroll
            for (int j = 0; j < 4; ++j) {
                const int row = bm + wr * 64 + m * 16 + cr + j;
                float v = acc[m][n][j] + bv;
                if (epi == 1) {
                    float x = v + cb[col];
                    v = fmaxf(0.f, gam[col] * (x - mu[col]) * rsqrtf(va[col] + 1e-5f) + bet[col]);
                }
                if (epi == 2) {
                    ((unsigned short*)Cv)[(size_t)row * ldc + col] = f2bf(v);
                } else if (epi == 3) {
                    const int bb2 = row >> 8, ss = row & 255, hh = col >> 7, dd = col & 127;
                    ((unsigned short*)Cv)[((size_t)(bb2 * 4 + hh) * 128 + dd) * 256 + ss] = f2bf(v);
                } else if (epi == 4) {
                    if (col < 80) ((float*)Cv)[(size_t)row * ldc + col] = v;
                } else {
                    ((float*)Cv)[(size_t)row * ldc + col] = v;
                }
            }
        }
}

// ---------------- fused decoder layer: GEMM(3 gates) + LSTM cell -----------
// Weight layout [i;g;o] (3x1024 rows x K). Block = (hid-tile bnh, row-tile bm).
// 3 sequential K-loops (same A tile, B offset gate*1024 rows). Lane's acc
// element maps to the SAME (row,hid) for every gate -> i,g parked in regs
// (packed bf16), cell computed in final epilogue. No gates buffer, no cell
// kernel, saves ~157MB HBM round-trip per layer.
__global__ __launch_bounds__(256) void dec_fused(
    const unsigned short* __restrict__ A, const unsigned short* __restrict__ Bw,
    const float* __restrict__ bias, unsigned short* __restrict__ hout,
    int K)
{
    __shared__ unsigned short As[4096];
    __shared__ unsigned short Bs[4096];
    const int tid = threadIdx.x, w = tid >> 6, lane = tid & 63;
    const int bnh = blockIdx.x * 128, bm = blockIdx.y * 128;
    const int wr = w >> 1, wc = w & 1;
    const int r0 = w * 16 + (lane >> 2);
    const int k8 = (lane & 3) * 8;
    const int cr = (lane >> 4) * 4, ccol = lane & 15;

    unsigned int ig[4][4][4];
    f32x4 acc[4][4];

    const unsigned short* Ag = A + (size_t)(bm + r0) * K + k8;
    unsigned short* Al = As + w * 512;
    unsigned short* Bl = Bs + w * 512;

    for (int gate = 0; gate < 3; ++gate) {
#pragma unroll
        for (int m = 0; m < 4; ++m)
#pragma unroll
            for (int n = 0; n < 4; ++n) acc[m][n] = (f32x4){0.f, 0.f, 0.f, 0.f};

        const unsigned short* Bg = Bw + (size_t)(gate * 1024 + bnh + r0) * K + k8;
        for (int k0 = 0; k0 < K; k0 += 32) {
            __syncthreads();
            gl_lds16(Ag + k0, Al);
            gl_lds16(Ag + (size_t)64 * K + k0, Al + 2048);
            gl_lds16(Bg + k0, Bl);
            gl_lds16(Bg + (size_t)64 * K + k0, Bl + 2048);
            __syncthreads();
            bf16x8 a[4], b[4];
#pragma unroll
            for (int m = 0; m < 4; ++m)
                a[m] = *(const bf16x8*)(As + (wr * 64 + m * 16 + (lane & 15)) * 32 + (lane >> 4) * 8);
#pragma unroll
            for (int n = 0; n < 4; ++n)
                b[n] = *(const bf16x8*)(Bs + (wc * 64 + n * 16 + (lane & 15)) * 32 + (lane >> 4) * 8);
#pragma unroll
            for (int m = 0; m < 4; ++m)
#pragma unroll
                for (int n = 0; n < 4; ++n)
                    acc[m][n] = __builtin_amdgcn_mfma_f32_16x16x32_bf16(a[m], b[n], acc[m][n], 0, 0, 0);
        }

        if (gate == 0) {
#pragma unroll
            for (int m = 0; m < 4; ++m)
#pragma unroll
                for (int n = 0; n < 4; ++n)
#pragma unroll
                    for (int j = 0; j < 4; ++j)
                        ig[m][n][j] = (unsigned int)f2bf(acc[m][n][j]);
        } else if (gate == 1) {
#pragma unroll
            for (int m = 0; m < 4; ++m)
#pragma unroll
                for (int n = 0; n < 4; ++n)
#pragma unroll
                    for (int j = 0; j < 4; ++j)
                        ig[m][n][j] |= (unsigned int)f2bf(acc[m][n][j]) << 16;
        } else {
#pragma unroll
            for (int m = 0; m < 4; ++m)
#pragma unroll
                for (int n = 0; n < 4; ++n) {
                    const int jh = bnh + wc * 64 + n * 16 + ccol;
                    const float bi = bias[jh];
                    const float bg = bias[2048 + jh];
                    const float bo = bias[3072 + jh];
#pragma unroll
                    for (int j = 0; j < 4; ++j) {
                        const int row = bm + wr * 64 + m * 16 + cr + j;
                        float iv = sigf(bf2f((unsigned short)(ig[m][n][j] & 0xFFFF)) + bi);
                        float gv = tanhfast(bf2f((unsigned short)(ig[m][n][j] >> 16)) + bg);
                        float ov = sigf(acc[m][n][j] + bo);
                        hout[(size_t)row * 1024 + jh] = f2bf(ov * tanhfast(iv * gv));
                    }
                }
        }
    }
}

// ---------------- fused attention QK^T + row softmax -----------------------
__global__ __launch_bounds__(256) void attn_qksm(
    const unsigned short* __restrict__ q, const unsigned short* __restrict__ k,
    unsigned short* __restrict__ probs)
{
    __shared__ unsigned short As[2048];     // 64 rows x 32 k
    __shared__ unsigned short Bs[8192];     // 256 rows x 32 k
    __shared__ float redm[64][4];
    __shared__ float reds[64][4];
    const int tid = threadIdx.x, wid = tid >> 6, lane = tid & 63;
    const int l15 = lane & 15, bq = lane >> 4;
    const int bm = blockIdx.x * 64;
    const int z = blockIdx.y, b = z >> 2, h = z & 3;

    const unsigned short* A  = q + ((size_t)b * T_) * 512 + h * 128;
    const unsigned short* Bw = k + ((size_t)b * S_) * 512 + h * 128;

    f32x4 acc[4][4];
#pragma unroll
    for (int m = 0; m < 4; ++m)
#pragma unroll
        for (int n = 0; n < 4; ++n) acc[m][n] = (f32x4){0.f, 0.f, 0.f, 0.f};

    const int r0 = wid * 16 + (lane >> 2);
    const int k8 = (lane & 3) * 8;

    for (int k0 = 0; k0 < 128; k0 += 32) {
        __syncthreads();
        gl_lds16(A + (size_t)(bm + r0) * 512 + k0 + k8, As + wid * 512);
        gl_lds16(Bw + (size_t)r0 * 512 + k0 + k8,          Bs + wid * 512);
        gl_lds16(Bw + (size_t)(64 + r0) * 512 + k0 + k8,   Bs + 2048 + wid * 512);
        gl_lds16(Bw + (size_t)(128 + r0) * 512 + k0 + k8,  Bs + 4096 + wid * 512);
        gl_lds16(Bw + (size_t)(192 + r0) * 512 + k0 + k8,  Bs + 6144 + wid * 512);
        __syncthreads();
        bf16x8 a[4], bb[4];
#pragma unroll
        for (int m = 0; m < 4; ++m)
            a[m] = *(const bf16x8*)(As + (m * 16 + l15) * 32 + bq * 8);
#pragma unroll
        for (int n = 0; n < 4; ++n)
            bb[n] = *(const bf16x8*)(Bs + (wid * 64 + n * 16 + l15) * 32 + bq * 8);
#pragma unroll
        for (int m = 0; m < 4; ++m)
#pragma unroll
            for (int n = 0; n < 4; ++n)
                acc[m][n] = __builtin_amdgcn_mfma_f32_16x16x32_bf16(a[m], bb[n], acc[m][n], 0, 0, 0);
    }

    const int cr = (lane >> 4) * 4, ccol = lane & 15;
    const float SC = 0.08838834764831843f;

    float lmax[4][4];
#pragma unroll
    for (int m = 0; m < 4; ++m)
#pragma unroll
        for (int j = 0; j < 4; ++j) {
            float v = fmaxf(fmaxf(acc[m][0][j], acc[m][1][j]),
                            fmaxf(acc[m][2][j], acc[m][3][j]));
#pragma unroll
            for (int off = 1; off < 16; off <<= 1) v = fmaxf(v, __shfl_xor(v, off));
            lmax[m][j] = v;
            if (ccol == 0) redm[m * 16 + cr + j][wid] = v;
        }
    __syncthreads();
    float lsum[4][4];
#pragma unroll
    for (int m = 0; m < 4; ++m)
#pragma unroll
        for (int j = 0; j < 4; ++j) {
            const int r = m * 16 + cr + j;
            float mx = fmaxf(fmaxf(redm[r][0], redm[r][1]), fmaxf(redm[r][2], redm[r][3]));
            lmax[m][j] = mx;
            float s = 0.f;
#pragma unroll
            for (int n = 0; n < 4; ++n) {
                float p = __expf((acc[m][n][j] - mx) * SC);
                acc[m][n][j] = p;
                s += p;
            }
#pragma unroll
            for (int off = 1; off < 16; off <<= 1) s += __shfl_xor(s, off);
            lsum[m][j] = s;
            if (ccol == 0) reds[r][wid] = s;
        }
    __syncthreads();
#pragma unroll
    for (int m = 0; m < 4; ++m)
#pragma unroll
        for (int j = 0; j < 4; ++j) {
            const int r = m * 16 + cr + j;
            const int row = bm + r;
            if (row >= T_) continue;
            const float inv = 1.f / (reds[r][0] + reds[r][1] + reds[r][2] + reds[r][3]);
#pragma unroll
            for (int n = 0; n < 4; ++n)
                probs[((size_t)z * T_ + row) * 256 + wid * 64 + n * 16 + ccol] =
                    f2bf(acc[m][n][j] * inv);
        }
}

// ---------------- attention PV --------------------------------------------
__global__ __launch_bounds__(256) void attn_pv(
    const unsigned short* __restrict__ probs, const unsigned short* __restrict__ vT,
    unsigned short* __restrict__ ctx)
{
    __shared__ unsigned short As[4096];
    __shared__ unsigned short Bs[4096];
    const int tid = threadIdx.x, w = tid >> 6, lane = tid & 63;
    const int bm = blockIdx.y * 128;
    const int z = blockIdx.z, b = z >> 2, h = z & 3;
    const int wr = w >> 1, wc = w & 1;

    const unsigned short* A  = probs + (size_t)z * T_ * 256;
    const unsigned short* Bw = vT + (size_t)z * 128 * 256;

    f32x4 acc[4][4];
#pragma unroll
    for (int m = 0; m < 4; ++m)
#pragma unroll
        for (int n = 0; n < 4; ++n) acc[m][n] = (f32x4){0.f, 0.f, 0.f, 0.f};

    const int r0 = w * 16 + (lane >> 2);
    const int k8 = (lane & 3) * 8;
    const unsigned short* Ag = A + (size_t)(bm + r0) * 256 + k8;
    const unsigned short* Bg = Bw + (size_t)r0 * 256 + k8;
    unsigned short* Al = As + w * 512;
    unsigned short* Bl = Bs + w * 512;

    for (int k0 = 0; k0 < 256; k0 += 32) {
        __syncthreads();
        gl_lds16(Ag + k0, Al);
        gl_lds16(Ag + (size_t)64 * 256 + k0, Al + 2048);
        gl_lds16(Bg + k0, Bl);
        gl_lds16(Bg + (size_t)64 * 256 + k0, Bl + 2048);
        __syncthreads();
        bf16x8 a[4], bfr[4];
#pragma unroll
        for (int m = 0; m < 4; ++m)
            a[m] = *(const bf16x8*)(As + (wr * 64 + m * 16 + (lane & 15)) * 32 + (lane >> 4) * 8);
#pragma unroll
        for (int n = 0; n < 4; ++n)
            bfr[n] = *(const bf16x8*)(Bs + (wc * 64 + n * 16 + (lane & 15)) * 32 + (lane >> 4) * 8);
#pragma unroll
        for (int m = 0; m < 4; ++m)
#pragma unroll
            for (int n = 0; n < 4; ++n)
                acc[m][n] = __builtin_amdgcn_mfma_f32_16x16x32_bf16(a[m], bfr[n], acc[m][n], 0, 0, 0);
    }

    const int cr = (lane >> 4) * 4, ccol = lane & 15;
#pragma unroll
    for (int m = 0; m < 4; ++m)
#pragma unroll
        for (int n = 0; n < 4; ++n) {
            const int col = wc * 64 + n * 16 + ccol;
#pragma unroll
            for (int j = 0; j < 4; ++j) {
                const int row = bm + wr * 64 + m * 16 + cr + j;
                if (row < T_)
                    ctx[((size_t)b * T_ + row) * 512 + h * 128 + col] = f2bf(acc[m][n][j]);
            }
        }
}

// ---------------- elementwise / conversion kernels -------------------------
__global__ void embed_k(const int* __restrict__ txt, const float* __restrict__ emb,
                        float* __restrict__ xs)
{
    int idx = blockIdx.x * 256 + threadIdx.x;
    if (idx >= B_ * S_ * D_) return;
    int bs = idx >> 9, dd = idx & 511;
    xs[idx] = emb[(size_t)txt[bs] * D_ + dd];
}

__global__ void im2col_bf(const float* __restrict__ in, unsigned short* __restrict__ out)
{
    int idx = blockIdx.x * 256 + threadIdx.x;
    if (idx >= B_ * S_ * 2560) return;
    int r = idx / 2560, cc = idx % 2560;
    int din = cc / 5, kk = cc % 5;
    int b = r >> 8, s = r & 255;
    int sp = s + kk - 2;
    float v = (sp >= 0 && sp < S_) ? in[((size_t)b * S_ + sp) * D_ + din] : 0.f;
    out[idx] = f2bf(v);
}

__global__ void transp_bf(const float* __restrict__ in, unsigned short* __restrict__ out)
{
    int idx = blockIdx.x * 256 + threadIdx.x;
    if (idx >= B_ * S_ * D_) return;
    int d = idx & 511;
    int sb = idx >> 9;
    int s = sb >> 4, b = sb & 15;
    out[idx] = f2bf(in[((size_t)b * S_ + s) * D_ + d]);
}

// hist (f16, [dir][b][s][256]) -> enc (bf16, [b][s][512])
__global__ void hist2enc(const _Float16* __restrict__ hist, unsigned short* __restrict__ enc)
{
    int idx = blockIdx.x * 256 + threadIdx.x;
    if (idx >= B_ * S_ * D_) return;
    int d = idx & 511;
    int bs = idx >> 9;
    int b = bs >> 8, s = bs & 255;
    int dir = d >> 8, hid = d & 255;
    enc[idx] = f2bf((float)hist[(((size_t)(dir * 16 + b) * 256 + s) * 256) + hid]);
}

// ---- single fused weight-conversion kernel ----
__global__ void cvt_all(
    const float* __restrict__ conv_w, const float* __restrict__ Wih_f,
    const float* __restrict__ Wih_b, const float* __restrict__ Wk,
    const float* __restrict__ Wv, const float* __restrict__ Wq,
    const float* __restrict__ Wo, const float* __restrict__ Wih1,
    const float* __restrict__ Wih2, const float* __restrict__ melW,
    unsigned short* __restrict__ cWc, unsigned short* __restrict__ cWif,
    unsigned short* __restrict__ cWib, unsigned short* __restrict__ cWk,
    unsigned short* __restrict__ cWv, unsigned short* __restrict__ cWq,
    unsigned short* __restrict__ cWo, unsigned short* __restrict__ cW1,
    unsigned short* __restrict__ cW2, unsigned short* __restrict__ cWm)
{
    int idx = blockIdx.x * 256 + threadIdx.x;
    if (idx < 3932160) { cWc[idx] = f2bf(conv_w[idx]); return; }
    idx -= 3932160;
    if (idx < 524288) { cWif[idx] = f2bf(Wih_f[idx]); return; }
    idx -= 524288;
    if (idx < 524288) { cWib[idx] = f2bf(Wih_b[idx]); return; }
    idx -= 524288;
    if (idx < 262144) { cWk[idx] = f2bf(Wk[idx]); return; }
    idx -= 262144;
    if (idx < 262144) { cWv[idx] = f2bf(Wv[idx]); return; }
    idx -= 262144;
    if (idx < 49152) {
        int r = idx / 96, k = idx - r * 96;
        cWq[idx] = (k < 80) ? f2bf(Wq[(size_t)r * 80 + k]) : 0;
        return;
    }
    idx -= 49152;
    if (idx < 262144) { cWo[idx] = f2bf(Wo[idx]); return; }
    idx -= 262144;
    if (idx < 1867776) {
        int n = idx / 608, k = idx - n * 608;
        int orig = (n < 1024) ? n : n + 1024;
        cW1[idx] = (k < 592) ? f2bf(Wih1[(size_t)orig * 592 + k]) : 0;
        return;
    }
    idx -= 1867776;
    if (idx < 3145728) {
        int n = idx >> 10, k = idx & 1023;
        int orig = (n < 1024) ? n : n + 1024;
        cW2[idx] = f2bf(Wih2[(size_t)orig * 1024 + k]);
        return;
    }
    idx -= 3145728;
    if (idx < 131072) {
        int r = idx >> 10, k = idx & 1023;
        cWm[idx] = (r < 80) ? f2bf(melW[(size_t)r * 1024 + k]) : 0;
        return;
    }
}

__global__ void decin_k2(const float* __restrict__ mel, unsigned short* __restrict__ din,
                         unsigned short* __restrict__ xcat)
{
    int idx = blockIdx.x * 256 + threadIdx.x;
    if (idx >= B_ * T_ * 96) return;
    int r = idx / 96, j = idx - r * 96;
    int b = r / T_, t = r - b * T_;
    float v = (j < M_ && t > 0) ? mel[((size_t)b * T_ + t - 1) * M_ + j] : 0.f;
    unsigned short bv = f2bf(v);
    din[(size_t)r * 96 + j] = bv;
    xcat[(size_t)r * 608 + 512 + j] = bv;
}

__global__ __launch_bounds__(256) void stop_head(
    const unsigned short* __restrict__ h2, const float* __restrict__ sw,
    const float* __restrict__ sb, float* __restrict__ out)
{
    int row = blockIdx.x * 4 + (threadIdx.x >> 6);
    int lane = threadIdx.x & 63;
    const unsigned short* hr = h2 + (size_t)row * H_;
    float acc = 0.f;
#pragma unroll
    for (int i = 0; i < H_; i += 64) acc += bf2f(hr[i + lane]) * sw[i + lane];
    for (int off = 32; off; off >>= 1) acc += __shfl_xor(acc, off);
    if (lane == 0) out[row] = acc + sb[0];
}

// ---------------- persistent LSTM: r7 structure (best: ~700us) -------------
__global__ __launch_bounds__(1024, 4) void lstm_persist9(
    const float* __restrict__ gi_f, const float* __restrict__ gi_b,
    const float* __restrict__ Wf, const float* __restrict__ Wb,
    _Float16* __restrict__ hist,               // [2][16][256][256] f16
    unsigned long long* __restrict__ hstage)   // [2 slot][2 dir][2 half][8 ba][128 hid]
{
    const int blk = blockIdx.x;
    const int dir = blk >> 1, half = blk & 1;
    const float* gi = dir ? gi_b : gi_f;
    const float* W  = dir ? Wb : Wf;
    const int tid = threadIdx.x, wid = tid >> 6, lane = tid & 63;
    const int l15 = lane & 15, q = lane >> 4;
    const int half4 = half * 4, ph4 = (half ^ 1) * 4;

    __shared__ _Float16 h_lds[16][264];
    __shared__ float exch[512][17];

    half8 wOA[4], wPA[4], wOB[4], wPB[4];
    {
        const int gt0 = wid >> 3, hb0 = wid & 7;
        const int gt1 = (wid + 16) >> 3;
        const float* wr0 = W + (size_t)(gt0 * 256 + half * 128 + hb0 * 16 + l15) * 256;
        const float* wr1 = W + (size_t)(gt1 * 256 + half * 128 + hb0 * 16 + l15) * 256;
#pragma unroll
        for (int i = 0; i < 4; ++i) {
            const int kO = (half4 + i) * 32 + q * 8;
            const int kP = (ph4 + i) * 32 + q * 8;
            half8 a, b, c, d;
#pragma unroll
            for (int j = 0; j < 8; ++j) {
                a[j] = (_Float16)wr0[kO + j];
                b[j] = (_Float16)wr0[kP + j];
                c[j] = (_Float16)wr1[kO + j];
                d[j] = (_Float16)wr1[kP + j];
            }
            wOA[i] = a; wPA[i] = b; wOB[i] = c; wPB[i] = d;
        }
    }
    for (int i = tid; i < 16 * 264; i += 1024) ((_Float16*)h_lds)[i] = (_Float16)0.f;
    for (int i = tid; i < 512 * 17; i += 1024) ((float*)exch)[i] = 0.f;

    const int hid = tid & 127;
    const int ba  = tid >> 7;       // 0..7
    const int bb  = ba + 8;
    const int gh  = half * 128 + hid;
    const int pc  = (half ^ 1) * 128 + hid;
    float c0 = 0.f, c1 = 0.f;

    const int exr0 = (wid >> 3) * 128 + (wid & 7) * 16 + l15;
    const int exr1 = ((wid + 16) >> 3) * 128 + (wid & 7) * 16 + l15;

    const int own_base = ((dir * 2 + half) * 8 + ba) * 128 + hid;
    const int par_base = ((dir * 2 + (half ^ 1)) * 8 + ba) * 128 + hid;

    float gp0[4], gp1[4];
    {
        const int s0 = dir ? 255 : 0;
        const float* g0 = gi + ((size_t)s0 * 16 + ba) * 1024 + gh;
        const float* g1 = gi + ((size_t)s0 * 16 + bb) * 1024 + gh;
#pragma unroll
        for (int g2 = 0; g2 < 4; ++g2) { gp0[g2] = g0[g2 * 256]; gp1[g2] = g1[g2 * 256]; }
    }
    __syncthreads();

    for (int step = 0; step < 256; ++step) {
        const int s = dir ? (255 - step) : step;
        const unsigned int tag = (unsigned int)(step + 1);
        const int slot = (step & 1) * 4096;

        float h0, h1;
        {
            float xi = exch[hid][ba] + gp0[0];
            float xf = exch[128 + hid][ba] + gp0[1];
            float xg = exch[256 + hid][ba] + gp0[2];
            float xo = exch[384 + hid][ba] + gp0[3];
            float ig = sigf(xi), fg = sigf(xf), gg = tanhfast(xg), og = sigf(xo);
            c0 = fg * c0 + ig * gg; h0 = og * tanhfast(c0);
            xi = exch[hid][bb] + gp1[0];
            xf = exch[128 + hid][bb] + gp1[1];
            xg = exch[256 + hid][bb] + gp1[2];
            xo = exch[384 + hid][bb] + gp1[3];
            ig = sigf(xi); fg = sigf(xf); gg = tanhfast(xg); og = sigf(xo);
            c1 = fg * c1 + ig * gg; h1 = og * tanhfast(c1);
        }
        {
            unsigned int d32 = (unsigned int)h2u((_Float16)h0) |
                               ((unsigned int)h2u((_Float16)h1) << 16);
            unsigned long long wv = ((unsigned long long)tag << 32) | d32;
            __hip_atomic_store(&hstage[slot + own_base], wv,
                               __ATOMIC_RELAXED, __HIP_MEMORY_SCOPE_AGENT);
        }
        h_lds[ba][gh] = (_Float16)h0;
        h_lds[bb][gh] = (_Float16)h1;
        hist[(((size_t)(dir * 16 + ba) * 256 + s) * 256) + gh] = (_Float16)h0;
        hist[(((size_t)(dir * 16 + bb) * 256 + s) * 256) + gh] = (_Float16)h1;
        if (step < 255) {
            const int s2 = dir ? (254 - step) : (step + 1);
            const float* g0 = gi + ((size_t)s2 * 16 + ba) * 1024 + gh;
            const float* g1 = gi + ((size_t)s2 * 16 + bb) * 1024 + gh;
#pragma unroll
            for (int g2 = 0; g2 < 4; ++g2) { gp0[g2] = g0[g2 * 256]; gp1[g2] = g1[g2 * 256]; }
        }
        __syncthreads();

        if (step < 255) {
            f32x4 acc0 = (f32x4){0.f, 0.f, 0.f, 0.f};
            f32x4 acc1 = (f32x4){0.f, 0.f, 0.f, 0.f};
            const _Float16* hrow = &h_lds[l15][0];
#pragma unroll
            for (int i = 0; i < 4; ++i) {
                half8 a = *(const half8*)(hrow + (half4 + i) * 32 + q * 8);
                acc0 = __builtin_amdgcn_mfma_f32_16x16x32_f16(a, wOA[i], acc0, 0, 0, 0);
                acc1 = __builtin_amdgcn_mfma_f32_16x16x32_f16(a, wOB[i], acc1, 0, 0, 0);
            }
            {
                unsigned long long pv;
                do {
                    pv = __hip_atomic_load(&hstage[slot + par_base],
                                           __ATOMIC_RELAXED, __HIP_MEMORY_SCOPE_AGENT);
                } while ((unsigned int)(pv >> 32) != tag);
                unsigned int d32 = (unsigned int)pv;
                *(unsigned short*)&h_lds[ba][pc] = (unsigned short)(d32 & 0xFFFF);
                *(unsigned short*)&h_lds[bb][pc] = (unsigned short)(d32 >> 16);
            }
            __syncthreads();
#pragma unroll
            for (int i = 0; i < 4; ++i) {
                half8 a = *(const half8*)(hrow + (ph4 + i) * 32 + q * 8);
                acc0 = __builtin_amdgcn_mfma_f32_16x16x32_f16(a, wPA[i], acc0, 0, 0, 0);
                acc1 = __builtin_amdgcn_mfma_f32_16x16x32_f16(a, wPB[i], acc1, 0, 0, 0);
            }
            *(f32x4*)&exch[exr0][q * 4] = acc0;
            *(f32x4*)&exch[exr1][q * 4] = acc1;
            __syncthreads();
        }
    }
}

// ---------------- host orchestration --------------------------------------
static inline void launch_mfma(hipStream_t st, const unsigned short* A, const unsigned short* B,
                               void* C, const float* bias, int M, int N, int K, int ldc, int epi = 0,
                               const float* cb = nullptr, const float* gam = nullptr,
                               const float* bet = nullptr, const float* mu = nullptr,
                               const float* va = nullptr)
{
    dim3 grid(N / 128, M / 128);
    gemm_mfma<<<grid, 256, 0, st>>>(A, B, C, bias, M, N, K, ldc, epi, cb, gam, bet, mu, va);
}

extern "C" void kernel_launch(void* const* d_in, const int* in_sizes, int n_in,
                              void* d_out, int out_size, void* d_ws, size_t ws_size,
                              hipStream_t stream)
{
    const int*   text   = (const int*)d_in[0];
    const float* mel_t  = (const float*)d_in[1];
    const float* emb    = (const float*)d_in[2];
    const float* conv_w = (const float*)d_in[3];
    const float* conv_b = (const float*)d_in[4];
    const float* bn_g   = (const float*)d_in[5];
    const float* bn_b   = (const float*)d_in[6];
    const float* bn_m   = (const float*)d_in[7];
    const float* bn_v   = (const float*)d_in[8];
    const float* Wih_f  = (const float*)d_in[9];
    const float* Whh_f  = (const float*)d_in[10];
    const float* b_f    = (const float*)d_in[11];
    const float* Wih_b  = (const float*)d_in[12];
    const float* Whh_b  = (const float*)d_in[13];
    const float* b_b    = (const float*)d_in[14];
    const float* Wq     = (const float*)d_in[15];
    const float* bq     = (const float*)d_in[16];
    const float* Wk     = (const float*)d_in[17];
    const float* bk     = (const float*)d_in[18];
    const float* Wv     = (const float*)d_in[19];
    const float* bv     = (const float*)d_in[20];
    const float* Wo     = (const float*)d_in[21];
    const float* bo     = (const float*)d_in[22];
    const float* Wih1   = (const float*)d_in[23];
    const float* b1     = (const float*)d_in[24];
    const float* Wih2   = (const float*)d_in[25];
    const float* b2     = (const float*)d_in[26];
    const float* melW   = (const float*)d_in[27];
    const float* melb   = (const float*)d_in[28];
    const float* stopW  = (const float*)d_in[29];
    const float* stopb  = (const float*)d_in[30];
    float* out = (float*)d_out;
    (void)in_sizes; (void)n_in; (void)out_size; (void)ws_size;

    float* ws = (float*)d_ws;
    float* big  = ws;                       // 13107200 f: im2col | h2b/h1b
    float* pool = ws + 13107200;

    unsigned long long* hstage = (unsigned long long*)(ws + 6000000); // 8192 u64, 64KB

    // phase A/B (encoder)
    float*          gi_f   = pool + 0;
    float*          gi_b   = pool + 4194304;
    unsigned short* enc_bf = (unsigned short*)(pool + 8388608);
    float*          P0     = pool + 9437184;
    float*          P1     = pool + 11534336;
    unsigned short* xsT    = (unsigned short*)(pool + 13631488);
    _Float16*       hist   = (_Float16*)(pool + 14155776);     // 4MB f16
    // phase C (attention)
    unsigned short* kbf    = (unsigned short*)(pool + 0);
    unsigned short* vT     = (unsigned short*)(pool + 1048576);
    unsigned short* qbf    = (unsigned short*)(pool + 2097152);
    unsigned short* probs  = (unsigned short*)(pool + 9437184);
    unsigned short* dinb   = (unsigned short*)(pool + 16008192);
    unsigned short* ctxb   = (unsigned short*)(pool + 16622592);
    // phase D (decoder, fused)
    unsigned short* h2b    = (unsigned short*)big;                 // 12800x1024 bf16
    unsigned short* h1b    = (unsigned short*)(big + 4000000);     // 12800x1024 bf16
    unsigned short* xcat   = (unsigned short*)(pool + 19899392);
    // weights
    float*          WB     = pool + 23790592;
    unsigned short* cWc  = (unsigned short*)(WB + 0);
    unsigned short* cWif = (unsigned short*)(WB + 1966080);
    unsigned short* cWib = (unsigned short*)(WB + 2228224);
    unsigned short* cWk  = (unsigned short*)(WB + 2490368);
    unsigned short* cWv  = (unsigned short*)(WB + 2621440);
    unsigned short* cWq  = (unsigned short*)(WB + 2752512);
    unsigned short* cWo  = (unsigned short*)(WB + 2777088);
    unsigned short* cW1  = (unsigned short*)(WB + 2908160);
    unsigned short* cW2  = (unsigned short*)(WB + 3842048);
    unsigned short* cWm  = (unsigned short*)(WB + 5414912);   // 128x1024 bf16

    auto ceil256 = [](int n) { return (n + 255) / 256; };

    // zero tagged-word staging (tags must start != 1..256)
    hipMemsetAsync(hstage, 0, 8192 * 8, stream);

    // ---- fused weight conversions (1 launch) ----
    cvt_all<<<ceil256(10960896), 256, 0, stream>>>(
        conv_w, Wih_f, Wih_b, Wk, Wv, Wq, Wo, Wih1, Wih2, melW,
        cWc, cWif, cWib, cWk, cWv, cWq, cWo, cW1, cW2, cWm);

    // ---- encoder: embedding + 3 convs ----
    embed_k<<<ceil256(B_ * S_ * D_), 256, 0, stream>>>(text, emb, P0);
    float* cin = P0;
    float* cout = P1;
    for (int l = 0; l < 3; ++l) {
        im2col_bf<<<ceil256(B_ * S_ * 2560), 256, 0, stream>>>(cin, (unsigned short*)big);
        launch_mfma(stream, (unsigned short*)big, cWc + (size_t)l * 512 * 2560,
                    cout, nullptr, B_ * S_, 512, 2560, 512, 1,
                    conv_b + l * 512, bn_g + l * 512, bn_b + l * 512, bn_m + l * 512, bn_v + l * 512);
        float* tmp = cin; cin = cout; cout = tmp;
    }
    transp_bf<<<ceil256(B_ * S_ * D_), 256, 0, stream>>>(cin, xsT);

    // ---- encoder LSTM ----
    launch_mfma(stream, xsT, cWif, gi_f, b_f, S_ * B_, 1024, 512, 1024);
    launch_mfma(stream, xsT, cWib, gi_b, b_b, S_ * B_, 1024, 512, 1024);
    lstm_persist9<<<4, 1024, 0, stream>>>(gi_f, gi_b, Whh_f, Whh_b, hist, hstage);
    hist2enc<<<ceil256(B_ * S_ * D_), 256, 0, stream>>>(hist, enc_bf);

    // ---- attention projections ----
    launch_mfma(stream, enc_bf, cWk, kbf, bk, B_ * S_, 512, 512, 512, 2);
    launch_mfma(stream, enc_bf, cWv, vT, bv, B_ * S_, 512, 512, 0, 3);
    decin_k2<<<ceil256(B_ * T_ * 96), 256, 0, stream>>>(mel_t, dinb, xcat);
    launch_mfma(stream, dinb, cWq, qbf, bq, B_ * T_, 512, 96, 512, 2);

    // ---- attention: fused QK^T+softmax, then PV ----
    attn_qksm<<<dim3(13, 64), 256, 0, stream>>>(qbf, kbf, probs);
    attn_pv<<<dim3(1, 7, 64), 256, 0, stream>>>(probs, vT, ctxb);

    // ---- Wo projection -> xcat[:, 0:512) bf16 ----
    launch_mfma(stream, ctxb, cWo, xcat, bo, B_ * T_, 512, 512, 608, 2);

    // ---- decoder: fused GEMM(3 gates)+cell per layer ----
    {
        dim3 grid(8, B_ * T_ / 128);
        dec_fused<<<grid, 256, 0, stream>>>(xcat, cW1, b1, h1b, 608);
        dec_fused<<<grid, 256, 0, stream>>>(h1b, cW2, b2, h2b, 1024);
    }

    // ---- output heads (mel via MFMA, stop via reduction) ----
    launch_mfma(stream, h2b, cWm, out, melb, B_ * T_, 128, 1024, 80, 4);
    stop_head<<<(B_ * T_) / 4, 256, 0, stream>>>(h2b, stopW, stopb, out + (size_t)B_ * T_ * M_);
}

// Round 13
// 1584.541 us; speedup vs baseline: 1.1128x; 1.1128x over previous
//
#include <hip/hip_runtime.h>
#include <hip/hip_bf16.h>
#include <math.h>

#define B_ 16
#define S_ 256
#define T_ 800
#define V_ 256
#define D_ 512
#define M_ 80
#define H_ 1024
#define NH_ 4
#define HD_ 128
#define EH_ 256

using bf16x8 = __attribute__((ext_vector_type(8))) short;
using f32x4  = __attribute__((ext_vector_type(4))) float;
typedef _Float16 half8 __attribute__((ext_vector_type(8)));

__device__ __forceinline__ float sigf(float x) { return 1.f / (1.f + __expf(-x)); }
__device__ __forceinline__ float tanhfast(float x) {
    float e = __expf(2.f * x);
    return 1.f - 2.f / (e + 1.f);
}

__device__ __forceinline__ unsigned short f2bf(float f) {
    unsigned int u = __float_as_uint(f);
    unsigned int r = (u + 0x7FFFu + ((u >> 16) & 1u)) >> 16;
    return (unsigned short)r;
}
__device__ __forceinline__ float bf2f(unsigned short u) {
    return __uint_as_float(((unsigned int)u) << 16);
}
__device__ __forceinline__ unsigned short h2u(_Float16 x) {
    union { _Float16 f; unsigned short u; } c; c.f = x; return c.u;
}

__device__ __forceinline__ void gl_lds16(const unsigned short* g, unsigned short* l) {
    __builtin_amdgcn_global_load_lds((const __attribute__((address_space(1))) void*)g,
                                     (__attribute__((address_space(3))) void*)l, 16, 0, 0);
}

// ---------------- MFMA bf16 GEMM: C = A(M,K) @ B(N,K)^T --------------------
// epi: 0 fp32(+bias), 1 conv BN+ReLU fp32, 2 bf16(+bias), 3 v^T bf16, 4 fp32 col<80
__global__ __launch_bounds__(256) void gemm_mfma(
    const unsigned short* __restrict__ A, const unsigned short* __restrict__ Bw,
    void* __restrict__ Cv, const float* __restrict__ bias,
    int M, int N, int K, int ldc, int epi,
    const float* __restrict__ cb, const float* __restrict__ gam,
    const float* __restrict__ bet, const float* __restrict__ mu,
    const float* __restrict__ va)
{
    __shared__ unsigned short As[4096];
    __shared__ unsigned short Bs[4096];
    const int tid = threadIdx.x, w = tid >> 6, lane = tid & 63;
    const int bm = blockIdx.y * 128, bn = blockIdx.x * 128;
    const int wr = w >> 1, wc = w & 1;

    f32x4 acc[4][4];
#pragma unroll
    for (int m = 0; m < 4; ++m)
#pragma unroll
        for (int n = 0; n < 4; ++n) acc[m][n] = (f32x4){0.f, 0.f, 0.f, 0.f};

    const int r0 = w * 16 + (lane >> 2);
    const int k8 = (lane & 3) * 8;
    const unsigned short* Ag = A + (size_t)(bm + r0) * K + k8;
    const unsigned short* Bg = Bw + (size_t)(bn + r0) * K + k8;
    unsigned short* Al = As + w * 512;
    unsigned short* Bl = Bs + w * 512;

    for (int k0 = 0; k0 < K; k0 += 32) {
        __syncthreads();
        gl_lds16(Ag + k0, Al);
        gl_lds16(Ag + (size_t)64 * K + k0, Al + 2048);
        gl_lds16(Bg + k0, Bl);
        gl_lds16(Bg + (size_t)64 * K + k0, Bl + 2048);
        __syncthreads();
        bf16x8 a[4], b[4];
#pragma unroll
        for (int m = 0; m < 4; ++m)
            a[m] = *(const bf16x8*)(As + (wr * 64 + m * 16 + (lane & 15)) * 32 + (lane >> 4) * 8);
#pragma unroll
        for (int n = 0; n < 4; ++n)
            b[n] = *(const bf16x8*)(Bs + (wc * 64 + n * 16 + (lane & 15)) * 32 + (lane >> 4) * 8);
#pragma unroll
        for (int m = 0; m < 4; ++m)
#pragma unroll
            for (int n = 0; n < 4; ++n)
                acc[m][n] = __builtin_amdgcn_mfma_f32_16x16x32_bf16(a[m], b[n], acc[m][n], 0, 0, 0);
    }

    const int cr = (lane >> 4) * 4, ccol = lane & 15;
#pragma unroll
    for (int m = 0; m < 4; ++m)
#pragma unroll
        for (int n = 0; n < 4; ++n) {
            const int col = bn + wc * 64 + n * 16 + ccol;
            const float bv = (bias && !(epi == 4 && col >= 80)) ? bias[col] : 0.f;
#pragma unroll
            for (int j = 0; j < 4; ++j) {
                const int row = bm + wr * 64 + m * 16 + cr + j;
                float v = acc[m][n][j] + bv;
                if (epi == 1) {
                    float x = v + cb[col];
                    v = fmaxf(0.f, gam[col] * (x - mu[col]) * rsqrtf(va[col] + 1e-5f) + bet[col]);
                }
                if (epi == 2) {
                    ((unsigned short*)Cv)[(size_t)row * ldc + col] = f2bf(v);
                } else if (epi == 3) {
                    const int bb2 = row >> 8, ss = row & 255, hh = col >> 7, dd = col & 127;
                    ((unsigned short*)Cv)[((size_t)(bb2 * 4 + hh) * 128 + dd) * 256 + ss] = f2bf(v);
                } else if (epi == 4) {
                    if (col < 80) ((float*)Cv)[(size_t)row * ldc + col] = v;
                } else {
                    ((float*)Cv)[(size_t)row * ldc + col] = v;
                }
            }
        }
}

// ---------------- fused attention QK^T + row softmax -----------------------
__global__ __launch_bounds__(256) void attn_qksm(
    const unsigned short* __restrict__ q, const unsigned short* __restrict__ k,
    unsigned short* __restrict__ probs)
{
    __shared__ unsigned short As[2048];     // 64 rows x 32 k
    __shared__ unsigned short Bs[8192];     // 256 rows x 32 k
    __shared__ float redm[64][4];
    __shared__ float reds[64][4];
    const int tid = threadIdx.x, wid = tid >> 6, lane = tid & 63;
    const int l15 = lane & 15, bq = lane >> 4;
    const int bm = blockIdx.x * 64;
    const int z = blockIdx.y, b = z >> 2, h = z & 3;

    const unsigned short* A  = q + ((size_t)b * T_) * 512 + h * 128;
    const unsigned short* Bw = k + ((size_t)b * S_) * 512 + h * 128;

    f32x4 acc[4][4];
#pragma unroll
    for (int m = 0; m < 4; ++m)
#pragma unroll
        for (int n = 0; n < 4; ++n) acc[m][n] = (f32x4){0.f, 0.f, 0.f, 0.f};

    const int r0 = wid * 16 + (lane >> 2);
    const int k8 = (lane & 3) * 8;

    for (int k0 = 0; k0 < 128; k0 += 32) {
        __syncthreads();
        gl_lds16(A + (size_t)(bm + r0) * 512 + k0 + k8, As + wid * 512);
        gl_lds16(Bw + (size_t)r0 * 512 + k0 + k8,          Bs + wid * 512);
        gl_lds16(Bw + (size_t)(64 + r0) * 512 + k0 + k8,   Bs + 2048 + wid * 512);
        gl_lds16(Bw + (size_t)(128 + r0) * 512 + k0 + k8,  Bs + 4096 + wid * 512);
        gl_lds16(Bw + (size_t)(192 + r0) * 512 + k0 + k8,  Bs + 6144 + wid * 512);
        __syncthreads();
        bf16x8 a[4], bb[4];
#pragma unroll
        for (int m = 0; m < 4; ++m)
            a[m] = *(const bf16x8*)(As + (m * 16 + l15) * 32 + bq * 8);
#pragma unroll
        for (int n = 0; n < 4; ++n)
            bb[n] = *(const bf16x8*)(Bs + (wid * 64 + n * 16 + l15) * 32 + bq * 8);
#pragma unroll
        for (int m = 0; m < 4; ++m)
#pragma unroll
            for (int n = 0; n < 4; ++n)
                acc[m][n] = __builtin_amdgcn_mfma_f32_16x16x32_bf16(a[m], bb[n], acc[m][n], 0, 0, 0);
    }

    const int cr = (lane >> 4) * 4, ccol = lane & 15;
    const float SC = 0.08838834764831843f;

    float lmax[4][4];
#pragma unroll
    for (int m = 0; m < 4; ++m)
#pragma unroll
        for (int j = 0; j < 4; ++j) {
            float v = fmaxf(fmaxf(acc[m][0][j], acc[m][1][j]),
                            fmaxf(acc[m][2][j], acc[m][3][j]));
#pragma unroll
            for (int off = 1; off < 16; off <<= 1) v = fmaxf(v, __shfl_xor(v, off));
            lmax[m][j] = v;
            if (ccol == 0) redm[m * 16 + cr + j][wid] = v;
        }
    __syncthreads();
    float lsum[4][4];
#pragma unroll
    for (int m = 0; m < 4; ++m)
#pragma unroll
        for (int j = 0; j < 4; ++j) {
            const int r = m * 16 + cr + j;
            float mx = fmaxf(fmaxf(redm[r][0], redm[r][1]), fmaxf(redm[r][2], redm[r][3]));
            lmax[m][j] = mx;
            float s = 0.f;
#pragma unroll
            for (int n = 0; n < 4; ++n) {
                float p = __expf((acc[m][n][j] - mx) * SC);
                acc[m][n][j] = p;
                s += p;
            }
#pragma unroll
            for (int off = 1; off < 16; off <<= 1) s += __shfl_xor(s, off);
            lsum[m][j] = s;
            if (ccol == 0) reds[r][wid] = s;
        }
    __syncthreads();
#pragma unroll
    for (int m = 0; m < 4; ++m)
#pragma unroll
        for (int j = 0; j < 4; ++j) {
            const int r = m * 16 + cr + j;
            const int row = bm + r;
            if (row >= T_) continue;
            const float inv = 1.f / (reds[r][0] + reds[r][1] + reds[r][2] + reds[r][3]);
#pragma unroll
            for (int n = 0; n < 4; ++n)
                probs[((size_t)z * T_ + row) * 256 + wid * 64 + n * 16 + ccol] =
                    f2bf(acc[m][n][j] * inv);
        }
}

// ---------------- attention PV --------------------------------------------
__global__ __launch_bounds__(256) void attn_pv(
    const unsigned short* __restrict__ probs, const unsigned short* __restrict__ vT,
    unsigned short* __restrict__ ctx)
{
    __shared__ unsigned short As[4096];
    __shared__ unsigned short Bs[4096];
    const int tid = threadIdx.x, w = tid >> 6, lane = tid & 63;
    const int bm = blockIdx.y * 128;
    const int z = blockIdx.z, b = z >> 2, h = z & 3;
    const int wr = w >> 1, wc = w & 1;

    const unsigned short* A  = probs + (size_t)z * T_ * 256;
    const unsigned short* Bw = vT + (size_t)z * 128 * 256;

    f32x4 acc[4][4];
#pragma unroll
    for (int m = 0; m < 4; ++m)
#pragma unroll
        for (int n = 0; n < 4; ++n) acc[m][n] = (f32x4){0.f, 0.f, 0.f, 0.f};

    const int r0 = w * 16 + (lane >> 2);
    const int k8 = (lane & 3) * 8;
    const unsigned short* Ag = A + (size_t)(bm + r0) * 256 + k8;
    const unsigned short* Bg = Bw + (size_t)r0 * 256 + k8;
    unsigned short* Al = As + w * 512;
    unsigned short* Bl = Bs + w * 512;

    for (int k0 = 0; k0 < 256; k0 += 32) {
        __syncthreads();
        gl_lds16(Ag + k0, Al);
        gl_lds16(Ag + (size_t)64 * 256 + k0, Al + 2048);
        gl_lds16(Bg + k0, Bl);
        gl_lds16(Bg + (size_t)64 * 256 + k0, Bl + 2048);
        __syncthreads();
        bf16x8 a[4], bfr[4];
#pragma unroll
        for (int m = 0; m < 4; ++m)
            a[m] = *(const bf16x8*)(As + (wr * 64 + m * 16 + (lane & 15)) * 32 + (lane >> 4) * 8);
#pragma unroll
        for (int n = 0; n < 4; ++n)
            bfr[n] = *(const bf16x8*)(Bs + (wc * 64 + n * 16 + (lane & 15)) * 32 + (lane >> 4) * 8);
#pragma unroll
        for (int m = 0; m < 4; ++m)
#pragma unroll
            for (int n = 0; n < 4; ++n)
                acc[m][n] = __builtin_amdgcn_mfma_f32_16x16x32_bf16(a[m], bfr[n], acc[m][n], 0, 0, 0);
    }

    const int cr = (lane >> 4) * 4, ccol = lane & 15;
#pragma unroll
    for (int m = 0; m < 4; ++m)
#pragma unroll
        for (int n = 0; n < 4; ++n) {
            const int col = wc * 64 + n * 16 + ccol;
#pragma unroll
            for (int j = 0; j < 4; ++j) {
                const int row = bm + wr * 64 + m * 16 + cr + j;
                if (row < T_)
                    ctx[((size_t)b * T_ + row) * 512 + h * 128 + col] = f2bf(acc[m][n][j]);
            }
        }
}

// ---------------- elementwise / conversion kernels -------------------------
__global__ void im2col_bf(const float* __restrict__ in, unsigned short* __restrict__ out)
{
    int idx = blockIdx.x * 256 + threadIdx.x;
    if (idx >= B_ * S_ * 2560) return;
    int r = idx / 2560, cc = idx % 2560;
    int din = cc / 5, kk = cc % 5;
    int b = r >> 8, s = r & 255;
    int sp = s + kk - 2;
    float v = (sp >= 0 && sp < S_) ? in[((size_t)b * S_ + sp) * D_ + din] : 0.f;
    out[idx] = f2bf(v);
}

__global__ void transp_bf(const float* __restrict__ in, unsigned short* __restrict__ out)
{
    int idx = blockIdx.x * 256 + threadIdx.x;
    if (idx >= B_ * S_ * D_) return;
    int d = idx & 511;
    int sb = idx >> 9;
    int s = sb >> 4, b = sb & 15;
    out[idx] = f2bf(in[((size_t)b * S_ + s) * D_ + d]);
}

// hist (f16, [dir][b][s][256]) -> enc (bf16, [b][s][512])
__global__ void hist2enc(const _Float16* __restrict__ hist, unsigned short* __restrict__ enc)
{
    int idx = blockIdx.x * 256 + threadIdx.x;
    if (idx >= B_ * S_ * D_) return;
    int d = idx & 511;
    int bs = idx >> 9;
    int b = bs >> 8, s = bs & 255;
    int dir = d >> 8, hid = d & 255;
    enc[idx] = f2bf((float)hist[(((size_t)(dir * 16 + b) * 256 + s) * 256) + hid]);
}

// ---- single fused prologue kernel: weight conversions + embed + decin ----
__global__ void cvt_all(
    const float* __restrict__ conv_w, const float* __restrict__ Wih_f,
    const float* __restrict__ Wih_b, const float* __restrict__ Wk,
    const float* __restrict__ Wv, const float* __restrict__ Wq,
    const float* __restrict__ Wo, const float* __restrict__ Wih1,
    const float* __restrict__ Wih2, const float* __restrict__ melW,
    const int* __restrict__ txt, const float* __restrict__ emb,
    const float* __restrict__ mel,
    unsigned short* __restrict__ cWc, unsigned short* __restrict__ cWif,
    unsigned short* __restrict__ cWib, unsigned short* __restrict__ cWk,
    unsigned short* __restrict__ cWv, unsigned short* __restrict__ cWq,
    unsigned short* __restrict__ cWo, unsigned short* __restrict__ cW1,
    unsigned short* __restrict__ cW2, unsigned short* __restrict__ cWm,
    float* __restrict__ xs, unsigned short* __restrict__ din,
    unsigned short* __restrict__ xcat)
{
    int idx = blockIdx.x * 256 + threadIdx.x;
    if (idx < 3932160) { cWc[idx] = f2bf(conv_w[idx]); return; }
    idx -= 3932160;
    if (idx < 524288) { cWif[idx] = f2bf(Wih_f[idx]); return; }
    idx -= 524288;
    if (idx < 524288) { cWib[idx] = f2bf(Wih_b[idx]); return; }
    idx -= 524288;
    if (idx < 262144) { cWk[idx] = f2bf(Wk[idx]); return; }
    idx -= 262144;
    if (idx < 262144) { cWv[idx] = f2bf(Wv[idx]); return; }
    idx -= 262144;
    if (idx < 49152) {
        int r = idx / 96, k = idx - r * 96;
        cWq[idx] = (k < 80) ? f2bf(Wq[(size_t)r * 80 + k]) : 0;
        return;
    }
    idx -= 49152;
    if (idx < 262144) { cWo[idx] = f2bf(Wo[idx]); return; }
    idx -= 262144;
    if (idx < 1867776) {
        int n = idx / 608, k = idx - n * 608;
        int orig = (n < 1024) ? n : n + 1024;
        cW1[idx] = (k < 592) ? f2bf(Wih1[(size_t)orig * 592 + k]) : 0;
        return;
    }
    idx -= 1867776;
    if (idx < 3145728) {
        int n = idx >> 10, k = idx & 1023;
        int orig = (n < 1024) ? n : n + 1024;
        cW2[idx] = f2bf(Wih2[(size_t)orig * 1024 + k]);
        return;
    }
    idx -= 3145728;
    if (idx < 131072) {
        int r = idx >> 10, k = idx & 1023;
        cWm[idx] = (r < 80) ? f2bf(melW[(size_t)r * 1024 + k]) : 0;
        return;
    }
    idx -= 131072;
    if (idx < B_ * S_ * D_) {   // embedding gather
        int bs = idx >> 9, dd = idx & 511;
        xs[idx] = emb[(size_t)txt[bs] * D_ + dd];
        return;
    }
    idx -= B_ * S_ * D_;
    if (idx < B_ * T_ * 96) {   // decoder input (prev mel frame) + xcat tail
        int r = idx / 96, j = idx - r * 96;
        int b = r / T_, t = r - b * T_;
        float v = (j < M_ && t > 0) ? mel[((size_t)b * T_ + t - 1) * M_ + j] : 0.f;
        unsigned short bv = f2bf(v);
        din[(size_t)r * 96 + j] = bv;
        xcat[(size_t)r * 608 + 512 + j] = bv;
        return;
    }
}

// decoder cell: gates bf16 [rows][3072] = [i;g;o], out bf16; 2 cols/thread
__global__ void dec_cellb2(const unsigned short* __restrict__ g, const float* __restrict__ b,
                           unsigned short* __restrict__ h, int rows)
{
    int idx = blockIdx.x * 256 + threadIdx.x;
    if (idx >= rows * 512) return;
    int r = idx >> 9, j2 = (idx & 511) * 2;
    const unsigned short* gr = g + (size_t)r * 3072;
    ushort2 vi = *(const ushort2*)(gr + j2);
    ushort2 vg = *(const ushort2*)(gr + 1024 + j2);
    ushort2 vo = *(const ushort2*)(gr + 2048 + j2);
    float i0 = sigf(bf2f(vi.x) + b[j2]),          i1 = sigf(bf2f(vi.y) + b[j2 + 1]);
    float g0 = tanhfast(bf2f(vg.x) + b[2048 + j2]), g1 = tanhfast(bf2f(vg.y) + b[2048 + j2 + 1]);
    float o0 = sigf(bf2f(vo.x) + b[3072 + j2]),   o1 = sigf(bf2f(vo.y) + b[3072 + j2 + 1]);
    ushort2 o;
    o.x = f2bf(o0 * tanhfast(i0 * g0));
    o.y = f2bf(o1 * tanhfast(i1 * g1));
    *(ushort2*)(h + (size_t)r * 1024 + j2) = o;
}

__global__ __launch_bounds__(256) void stop_head(
    const unsigned short* __restrict__ h2, const float* __restrict__ sw,
    const float* __restrict__ sb, float* __restrict__ out)
{
    int row = blockIdx.x * 4 + (threadIdx.x >> 6);
    int lane = threadIdx.x & 63;
    const unsigned short* hr = h2 + (size_t)row * H_;
    float acc = 0.f;
#pragma unroll
    for (int i = 0; i < H_; i += 64) acc += bf2f(hr[i + lane]) * sw[i + lane];
    for (int off = 32; off; off >>= 1) acc += __shfl_xor(acc, off);
    if (lane == 0) out[row] = acc + sb[0];
}

// ---------------- persistent LSTM: r7/r11 structure (best: ~700us) ---------
__global__ __launch_bounds__(1024, 4) void lstm_persist9(
    const float* __restrict__ gi_f, const float* __restrict__ gi_b,
    const float* __restrict__ Wf, const float* __restrict__ Wb,
    _Float16* __restrict__ hist,               // [2][16][256][256] f16
    unsigned long long* __restrict__ hstage)   // [2 slot][2 dir][2 half][8 ba][128 hid]
{
    const int blk = blockIdx.x;
    const int dir = blk >> 1, half = blk & 1;
    const float* gi = dir ? gi_b : gi_f;
    const float* W  = dir ? Wb : Wf;
    const int tid = threadIdx.x, wid = tid >> 6, lane = tid & 63;
    const int l15 = lane & 15, q = lane >> 4;
    const int half4 = half * 4, ph4 = (half ^ 1) * 4;

    __shared__ _Float16 h_lds[16][264];
    __shared__ float exch[512][17];

    half8 wOA[4], wPA[4], wOB[4], wPB[4];
    {
        const int gt0 = wid >> 3, hb0 = wid & 7;
        const int gt1 = (wid + 16) >> 3;
        const float* wr0 = W + (size_t)(gt0 * 256 + half * 128 + hb0 * 16 + l15) * 256;
        const float* wr1 = W + (size_t)(gt1 * 256 + half * 128 + hb0 * 16 + l15) * 256;
#pragma unroll
        for (int i = 0; i < 4; ++i) {
            const int kO = (half4 + i) * 32 + q * 8;
            const int kP = (ph4 + i) * 32 + q * 8;
            half8 a, b, c, d;
#pragma unroll
            for (int j = 0; j < 8; ++j) {
                a[j] = (_Float16)wr0[kO + j];
                b[j] = (_Float16)wr0[kP + j];
                c[j] = (_Float16)wr1[kO + j];
                d[j] = (_Float16)wr1[kP + j];
            }
            wOA[i] = a; wPA[i] = b; wOB[i] = c; wPB[i] = d;
        }
    }
    for (int i = tid; i < 16 * 264; i += 1024) ((_Float16*)h_lds)[i] = (_Float16)0.f;
    for (int i = tid; i < 512 * 17; i += 1024) ((float*)exch)[i] = 0.f;

    const int hid = tid & 127;
    const int ba  = tid >> 7;       // 0..7
    const int bb  = ba + 8;
    const int gh  = half * 128 + hid;
    const int pc  = (half ^ 1) * 128 + hid;
    float c0 = 0.f, c1 = 0.f;

    const int exr0 = (wid >> 3) * 128 + (wid & 7) * 16 + l15;
    const int exr1 = ((wid + 16) >> 3) * 128 + (wid & 7) * 16 + l15;

    const int own_base = ((dir * 2 + half) * 8 + ba) * 128 + hid;
    const int par_base = ((dir * 2 + (half ^ 1)) * 8 + ba) * 128 + hid;

    float gp0[4], gp1[4];
    {
        const int s0 = dir ? 255 : 0;
        const float* g0 = gi + ((size_t)s0 * 16 + ba) * 1024 + gh;
        const float* g1 = gi + ((size_t)s0 * 16 + bb) * 1024 + gh;
#pragma unroll
        for (int g2 = 0; g2 < 4; ++g2) { gp0[g2] = g0[g2 * 256]; gp1[g2] = g1[g2 * 256]; }
    }
    __syncthreads();

    for (int step = 0; step < 256; ++step) {
        const int s = dir ? (255 - step) : step;
        const unsigned int tag = (unsigned int)(step + 1);
        const int slot = (step & 1) * 4096;

        float h0, h1;
        {
            float xi = exch[hid][ba] + gp0[0];
            float xf = exch[128 + hid][ba] + gp0[1];
            float xg = exch[256 + hid][ba] + gp0[2];
            float xo = exch[384 + hid][ba] + gp0[3];
            float ig = sigf(xi), fg = sigf(xf), gg = tanhfast(xg), og = sigf(xo);
            c0 = fg * c0 + ig * gg; h0 = og * tanhfast(c0);
            xi = exch[hid][bb] + gp1[0];
            xf = exch[128 + hid][bb] + gp1[1];
            xg = exch[256 + hid][bb] + gp1[2];
            xo = exch[384 + hid][bb] + gp1[3];
            ig = sigf(xi); fg = sigf(xf); gg = tanhfast(xg); og = sigf(xo);
            c1 = fg * c1 + ig * gg; h1 = og * tanhfast(c1);
        }
        {
            unsigned int d32 = (unsigned int)h2u((_Float16)h0) |
                               ((unsigned int)h2u((_Float16)h1) << 16);
            unsigned long long wv = ((unsigned long long)tag << 32) | d32;
            __hip_atomic_store(&hstage[slot + own_base], wv,
                               __ATOMIC_RELAXED, __HIP_MEMORY_SCOPE_AGENT);
        }
        h_lds[ba][gh] = (_Float16)h0;
        h_lds[bb][gh] = (_Float16)h1;
        hist[(((size_t)(dir * 16 + ba) * 256 + s) * 256) + gh] = (_Float16)h0;
        hist[(((size_t)(dir * 16 + bb) * 256 + s) * 256) + gh] = (_Float16)h1;
        if (step < 255) {
            const int s2 = dir ? (254 - step) : (step + 1);
            const float* g0 = gi + ((size_t)s2 * 16 + ba) * 1024 + gh;
            const float* g1 = gi + ((size_t)s2 * 16 + bb) * 1024 + gh;
#pragma unroll
            for (int g2 = 0; g2 < 4; ++g2) { gp0[g2] = g0[g2 * 256]; gp1[g2] = g1[g2 * 256]; }
        }
        __syncthreads();

        if (step < 255) {
            f32x4 acc0 = (f32x4){0.f, 0.f, 0.f, 0.f};
            f32x4 acc1 = (f32x4){0.f, 0.f, 0.f, 0.f};
            const _Float16* hrow = &h_lds[l15][0];
#pragma unroll
            for (int i = 0; i < 4; ++i) {
                half8 a = *(const half8*)(hrow + (half4 + i) * 32 + q * 8);
                acc0 = __builtin_amdgcn_mfma_f32_16x16x32_f16(a, wOA[i], acc0, 0, 0, 0);
                acc1 = __builtin_amdgcn_mfma_f32_16x16x32_f16(a, wOB[i], acc1, 0, 0, 0);
            }
            {
                unsigned long long pv;
                do {
                    pv = __hip_atomic_load(&hstage[slot + par_base],
                                           __ATOMIC_RELAXED, __HIP_MEMORY_SCOPE_AGENT);
                } while ((unsigned int)(pv >> 32) != tag);
                unsigned int d32 = (unsigned int)pv;
                *(unsigned short*)&h_lds[ba][pc] = (unsigned short)(d32 & 0xFFFF);
                *(unsigned short*)&h_lds[bb][pc] = (unsigned short)(d32 >> 16);
            }
            __syncthreads();
#pragma unroll
            for (int i = 0; i < 4; ++i) {
                half8 a = *(const half8*)(hrow + (ph4 + i) * 32 + q * 8);
                acc0 = __builtin_amdgcn_mfma_f32_16x16x32_f16(a, wPA[i], acc0, 0, 0, 0);
                acc1 = __builtin_amdgcn_mfma_f32_16x16x32_f16(a, wPB[i], acc1, 0, 0, 0);
            }
            *(f32x4*)&exch[exr0][q * 4] = acc0;
            *(f32x4*)&exch[exr1][q * 4] = acc1;
            __syncthreads();
        }
    }
}

// ---------------- host orchestration --------------------------------------
static inline void launch_mfma(hipStream_t st, const unsigned short* A, const unsigned short* B,
                               void* C, const float* bias, int M, int N, int K, int ldc, int epi = 0,
                               const float* cb = nullptr, const float* gam = nullptr,
                               const float* bet = nullptr, const float* mu = nullptr,
                               const float* va = nullptr)
{
    dim3 grid(N / 128, M / 128);
    gemm_mfma<<<grid, 256, 0, st>>>(A, B, C, bias, M, N, K, ldc, epi, cb, gam, bet, mu, va);
}

extern "C" void kernel_launch(void* const* d_in, const int* in_sizes, int n_in,
                              void* d_out, int out_size, void* d_ws, size_t ws_size,
                              hipStream_t stream)
{
    const int*   text   = (const int*)d_in[0];
    const float* mel_t  = (const float*)d_in[1];
    const float* emb    = (const float*)d_in[2];
    const float* conv_w = (const float*)d_in[3];
    const float* conv_b = (const float*)d_in[4];
    const float* bn_g   = (const float*)d_in[5];
    const float* bn_b   = (const float*)d_in[6];
    const float* bn_m   = (const float*)d_in[7];
    const float* bn_v   = (const float*)d_in[8];
    const float* Wih_f  = (const float*)d_in[9];
    const float* Whh_f  = (const float*)d_in[10];
    const float* b_f    = (const float*)d_in[11];
    const float* Wih_b  = (const float*)d_in[12];
    const float* Whh_b  = (const float*)d_in[13];
    const float* b_b    = (const float*)d_in[14];
    const float* Wq     = (const float*)d_in[15];
    const float* bq     = (const float*)d_in[16];
    const float* Wk     = (const float*)d_in[17];
    const float* bk     = (const float*)d_in[18];
    const float* Wv     = (const float*)d_in[19];
    const float* bv     = (const float*)d_in[20];
    const float* Wo     = (const float*)d_in[21];
    const float* bo     = (const float*)d_in[22];
    const float* Wih1   = (const float*)d_in[23];
    const float* b1     = (const float*)d_in[24];
    const float* Wih2   = (const float*)d_in[25];
    const float* b2     = (const float*)d_in[26];
    const float* melW   = (const float*)d_in[27];
    const float* melb   = (const float*)d_in[28];
    const float* stopW  = (const float*)d_in[29];
    const float* stopb  = (const float*)d_in[30];
    float* out = (float*)d_out;
    (void)in_sizes; (void)n_in; (void)out_size; (void)ws_size;

    float* ws = (float*)d_ws;
    float* big  = ws;                       // 13107200 f: im2col | h2b/h1b
    float* pool = ws + 13107200;

    unsigned long long* hstage = (unsigned long long*)(ws + 6000000); // 8192 u64, 64KB

    // phase A/B (encoder)
    float*          gi_f   = pool + 0;
    float*          gi_b   = pool + 4194304;
    unsigned short* enc_bf = (unsigned short*)(pool + 8388608);
    float*          P0     = pool + 9437184;
    float*          P1     = pool + 11534336;
    unsigned short* xsT    = (unsigned short*)(pool + 13631488);
    _Float16*       hist   = (_Float16*)(pool + 14155776);     // 4MB f16
    // phase C (attention)
    unsigned short* kbf    = (unsigned short*)(pool + 0);
    unsigned short* vT     = (unsigned short*)(pool + 1048576);
    unsigned short* qbf    = (unsigned short*)(pool + 2097152);
    unsigned short* probs  = (unsigned short*)(pool + 9437184);
    unsigned short* dinb   = (unsigned short*)(pool + 16008192);
    unsigned short* ctxb   = (unsigned short*)(pool + 16622592);
    // phase D (decoder)
    unsigned short* gatesb = (unsigned short*)(pool + 0);          // 12800x3072 bf16
    unsigned short* h2b    = (unsigned short*)big;                 // 12800x1024 bf16
    unsigned short* h1b    = (unsigned short*)(big + 4000000);     // 12800x1024 bf16
    unsigned short* xcat   = (unsigned short*)(pool + 19899392);
    // weights
    float*          WB     = pool + 23790592;
    unsigned short* cWc  = (unsigned short*)(WB + 0);
    unsigned short* cWif = (unsigned short*)(WB + 1966080);
    unsigned short* cWib = (unsigned short*)(WB + 2228224);
    unsigned short* cWk  = (unsigned short*)(WB + 2490368);
    unsigned short* cWv  = (unsigned short*)(WB + 2621440);
    unsigned short* cWq  = (unsigned short*)(WB + 2752512);
    unsigned short* cWo  = (unsigned short*)(WB + 2777088);
    unsigned short* cW1  = (unsigned short*)(WB + 2908160);
    unsigned short* cW2  = (unsigned short*)(WB + 3842048);
    unsigned short* cWm  = (unsigned short*)(WB + 5414912);   // 128x1024 bf16

    auto ceil256 = [](int n) { return (n + 255) / 256; };

    // zero tagged-word staging (tags must start != 1..256)
    hipMemsetAsync(hstage, 0, 8192 * 8, stream);

    // ---- fused prologue: weight conversions + embedding + decoder input ----
    cvt_all<<<ceil256(10960896 + B_ * S_ * D_ + B_ * T_ * 96), 256, 0, stream>>>(
        conv_w, Wih_f, Wih_b, Wk, Wv, Wq, Wo, Wih1, Wih2, melW,
        text, emb, mel_t,
        cWc, cWif, cWib, cWk, cWv, cWq, cWo, cW1, cW2, cWm,
        P0, dinb, xcat);

    // ---- encoder: 3 convs ----
    float* cin = P0;
    float* cout = P1;
    for (int l = 0; l < 3; ++l) {
        im2col_bf<<<ceil256(B_ * S_ * 2560), 256, 0, stream>>>(cin, (unsigned short*)big);
        launch_mfma(stream, (unsigned short*)big, cWc + (size_t)l * 512 * 2560,
                    cout, nullptr, B_ * S_, 512, 2560, 512, 1,
                    conv_b + l * 512, bn_g + l * 512, bn_b + l * 512, bn_m + l * 512, bn_v + l * 512);
        float* tmp = cin; cin = cout; cout = tmp;
    }
    transp_bf<<<ceil256(B_ * S_ * D_), 256, 0, stream>>>(cin, xsT);

    // ---- encoder LSTM ----
    launch_mfma(stream, xsT, cWif, gi_f, b_f, S_ * B_, 1024, 512, 1024);
    launch_mfma(stream, xsT, cWib, gi_b, b_b, S_ * B_, 1024, 512, 1024);
    lstm_persist9<<<4, 1024, 0, stream>>>(gi_f, gi_b, Whh_f, Whh_b, hist, hstage);
    hist2enc<<<ceil256(B_ * S_ * D_), 256, 0, stream>>>(hist, enc_bf);

    // ---- attention projections ----
    launch_mfma(stream, enc_bf, cWk, kbf, bk, B_ * S_, 512, 512, 512, 2);
    launch_mfma(stream, enc_bf, cWv, vT, bv, B_ * S_, 512, 512, 0, 3);
    launch_mfma(stream, dinb, cWq, qbf, bq, B_ * T_, 512, 96, 512, 2);

    // ---- attention: fused QK^T+softmax, then PV ----
    attn_qksm<<<dim3(13, 64), 256, 0, stream>>>(qbf, kbf, probs);
    attn_pv<<<dim3(1, 7, 64), 256, 0, stream>>>(probs, vT, ctxb);

    // ---- Wo projection -> xcat[:, 0:512) bf16 ----
    launch_mfma(stream, ctxb, cWo, xcat, bo, B_ * T_, 512, 512, 608, 2);

    // ---- decoder (unchunked, bf16 gates, f-gate dropped; N=3072=[i;g;o]) ----
    launch_mfma(stream, xcat, cW1, gatesb, nullptr, B_ * T_, 3072, 608, 3072, 2);
    dec_cellb2<<<ceil256(B_ * T_ * 512), 256, 0, stream>>>(gatesb, b1, h1b, B_ * T_);
    launch_mfma(stream, h1b, cW2, gatesb, nullptr, B_ * T_, 3072, 1024, 3072, 2);
    dec_cellb2<<<ceil256(B_ * T_ * 512), 256, 0, stream>>>(gatesb, b2, h2b, B_ * T_);

    // ---- output heads (mel via MFMA, stop via reduction) ----
    launch_mfma(stream, h2b, cWm, out, melb, B_ * T_, 128, 1024, 80, 4);
    stop_head<<<(B_ * T_) / 4, 256, 0, stream>>>(h2b, stopW, stopb, out + (size_t)B_ * T_ * M_);
}

// Round 14
// 1333.370 us; speedup vs baseline: 1.3224x; 1.1884x over previous
//
#include <hip/hip_runtime.h>
#include <hip/hip_bf16.h>
#include <math.h>

#define B_ 16
#define S_ 256
#define T_ 800
#define V_ 256
#define D_ 512
#define M_ 80
#define H_ 1024
#define NH_ 4
#define HD_ 128
#define EH_ 256

using bf16x8 = __attribute__((ext_vector_type(8))) short;
using f32x4  = __attribute__((ext_vector_type(4))) float;
typedef _Float16 half8 __attribute__((ext_vector_type(8)));

__device__ __forceinline__ float sigf(float x) { return 1.f / (1.f + __expf(-x)); }
__device__ __forceinline__ float tanhfast(float x) {
    float e = __expf(2.f * x);
    return 1.f - 2.f / (e + 1.f);
}

__device__ __forceinline__ unsigned short f2bf(float f) {
    unsigned int u = __float_as_uint(f);
    unsigned int r = (u + 0x7FFFu + ((u >> 16) & 1u)) >> 16;
    return (unsigned short)r;
}
__device__ __forceinline__ float bf2f(unsigned short u) {
    return __uint_as_float(((unsigned int)u) << 16);
}
__device__ __forceinline__ unsigned short h2u(_Float16 x) {
    union { _Float16 f; unsigned short u; } c; c.f = x; return c.u;
}

__device__ __forceinline__ void gl_lds16(const unsigned short* g, unsigned short* l) {
    __builtin_amdgcn_global_load_lds((const __attribute__((address_space(1))) void*)g,
                                     (__attribute__((address_space(3))) void*)l, 16, 0, 0);
}

// ---------------- MFMA bf16 GEMM: C = A(M,K) @ B(N,K)^T --------------------
// epi: 0 fp32(+bias), 2 bf16(+bias), 4 mel+stop fused (col<80 mel, col==80 stop),
//      5 kv fused (col<512 k row-major; col>=512 v transposed)
// aperm: A row permutation r -> (r&15)*256 + (r>>4)  (B-major -> S-major)
__global__ __launch_bounds__(256) void gemm_mfma(
    const unsigned short* __restrict__ A, const unsigned short* __restrict__ Bw,
    void* __restrict__ Cv, const float* __restrict__ bias,
    int M, int N, int K, int ldc, int epi, int aperm,
    const float* __restrict__ cb)
{
    __shared__ unsigned short As[4096];
    __shared__ unsigned short Bs[4096];
    const int tid = threadIdx.x, w = tid >> 6, lane = tid & 63;
    const int bm = blockIdx.y * 128, bn = blockIdx.x * 128;
    const int wr = w >> 1, wc = w & 1;

    f32x4 acc[4][4];
#pragma unroll
    for (int m = 0; m < 4; ++m)
#pragma unroll
        for (int n = 0; n < 4; ++n) acc[m][n] = (f32x4){0.f, 0.f, 0.f, 0.f};

    const int r0 = w * 16 + (lane >> 2);
    const int k8 = (lane & 3) * 8;
    int ar0 = bm + r0, ar1 = bm + r0 + 64;
    if (aperm) {
        ar0 = ((ar0 & 15) << 8) | (ar0 >> 4);
        ar1 = ((ar1 & 15) << 8) | (ar1 >> 4);
    }
    const unsigned short* Ag0 = A + (size_t)ar0 * K + k8;
    const unsigned short* Ag1 = A + (size_t)ar1 * K + k8;
    const unsigned short* Bg = Bw + (size_t)(bn + r0) * K + k8;
    unsigned short* Al = As + w * 512;
    unsigned short* Bl = Bs + w * 512;

    for (int k0 = 0; k0 < K; k0 += 32) {
        __syncthreads();
        gl_lds16(Ag0 + k0, Al);
        gl_lds16(Ag1 + k0, Al + 2048);
        gl_lds16(Bg + k0, Bl);
        gl_lds16(Bg + (size_t)64 * K + k0, Bl + 2048);
        __syncthreads();
        bf16x8 a[4], b[4];
#pragma unroll
        for (int m = 0; m < 4; ++m)
            a[m] = *(const bf16x8*)(As + (wr * 64 + m * 16 + (lane & 15)) * 32 + (lane >> 4) * 8);
#pragma unroll
        for (int n = 0; n < 4; ++n)
            b[n] = *(const bf16x8*)(Bs + (wc * 64 + n * 16 + (lane & 15)) * 32 + (lane >> 4) * 8);
#pragma unroll
        for (int m = 0; m < 4; ++m)
#pragma unroll
            for (int n = 0; n < 4; ++n)
                acc[m][n] = __builtin_amdgcn_mfma_f32_16x16x32_bf16(a[m], b[n], acc[m][n], 0, 0, 0);
    }

    const int cr = (lane >> 4) * 4, ccol = lane & 15;
#pragma unroll
    for (int m = 0; m < 4; ++m)
#pragma unroll
        for (int n = 0; n < 4; ++n) {
            const int col = bn + wc * 64 + n * 16 + ccol;
            float bv;
            if (epi == 5)      bv = (col < 512) ? bias[col] : cb[col - 512];
            else if (epi == 4) bv = (col < 80) ? bias[col] : (col == 80 ? cb[0] : 0.f);
            else               bv = bias ? bias[col] : 0.f;
#pragma unroll
            for (int j = 0; j < 4; ++j) {
                const int row = bm + wr * 64 + m * 16 + cr + j;
                float v = acc[m][n][j] + bv;
                if (epi == 2) {
                    ((unsigned short*)Cv)[(size_t)row * ldc + col] = f2bf(v);
                } else if (epi == 5) {
                    if (col < 512) {
                        ((unsigned short*)Cv)[(size_t)row * 512 + col] = f2bf(v);
                    } else {
                        // vT sits 2097152 ushorts after kbf (same pool)
                        unsigned short* vTo = (unsigned short*)Cv + 2097152;
                        const int c2 = col - 512, hh = c2 >> 7, dd = c2 & 127;
                        const int bb2 = row >> 8, ss = row & 255;
                        vTo[((size_t)(bb2 * 4 + hh) * 128 + dd) * 256 + ss] = f2bf(v);
                    }
                } else if (epi == 4) {
                    if (col < 80)       ((float*)Cv)[(size_t)row * ldc + col] = v;
                    else if (col == 80) ((float*)Cv)[1024000 + row] = v;
                } else {
                    ((float*)Cv)[(size_t)row * ldc + col] = v;
                }
            }
        }
}

// ---------------- conv layer as implicit GEMM (kk-major weights) -----------
// A row r=(b,s); K-chunk k0 -> kk=k0>>9, d0=k0&511; source row s+kk-2 of the
// bf16 input (zero page when OOB -- per-lane global source address).
// Epilogue: +conv_b, BN, ReLU, bf16 out (B*S,512).
__global__ __launch_bounds__(256) void conv_mfma(
    const unsigned short* __restrict__ xin, const unsigned short* __restrict__ Bw,
    unsigned short* __restrict__ xout,
    const float* __restrict__ cb, const float* __restrict__ gam,
    const float* __restrict__ bet, const float* __restrict__ mu,
    const float* __restrict__ va, const unsigned short* __restrict__ zbuf)
{
    __shared__ unsigned short As[4096];
    __shared__ unsigned short Bs[4096];
    const int tid = threadIdx.x, w = tid >> 6, lane = tid & 63;
    const int bm = blockIdx.y * 128, bn = blockIdx.x * 128;
    const int wr = w >> 1, wc = w & 1;

    f32x4 acc[4][4];
#pragma unroll
    for (int m = 0; m < 4; ++m)
#pragma unroll
        for (int n = 0; n < 4; ++n) acc[m][n] = (f32x4){0.f, 0.f, 0.f, 0.f};

    const int r0 = w * 16 + (lane >> 2);
    const int k8 = (lane & 3) * 8;
    const int gr0 = bm + r0, gr1 = bm + r0 + 64;
    const int b0 = gr0 >> 8, s0 = gr0 & 255;
    const int b1 = gr1 >> 8, s1 = gr1 & 255;
    const unsigned short* Bg = Bw + (size_t)(bn + r0) * 2560 + k8;
    unsigned short* Al = As + w * 512;
    unsigned short* Bl = Bs + w * 512;

    for (int k0 = 0; k0 < 2560; k0 += 32) {
        const int kk = k0 >> 9;
        const int d0 = k0 & 511;
        const int s2a = s0 + kk - 2;
        const int s2b = s1 + kk - 2;
        const unsigned short* pa = (s2a >= 0 && s2a < 256)
            ? xin + ((size_t)(b0 * 256 + s2a) * 512 + d0 + k8) : zbuf;
        const unsigned short* pb = (s2b >= 0 && s2b < 256)
            ? xin + ((size_t)(b1 * 256 + s2b) * 512 + d0 + k8) : zbuf;
        __syncthreads();
        gl_lds16(pa, Al);
        gl_lds16(pb, Al + 2048);
        gl_lds16(Bg + k0, Bl);
        gl_lds16(Bg + (size_t)64 * 2560 + k0, Bl + 2048);
        __syncthreads();
        bf16x8 a[4], b[4];
#pragma unroll
        for (int m = 0; m < 4; ++m)
            a[m] = *(const bf16x8*)(As + (wr * 64 + m * 16 + (lane & 15)) * 32 + (lane >> 4) * 8);
#pragma unroll
        for (int n = 0; n < 4; ++n)
            b[n] = *(const bf16x8*)(Bs + (wc * 64 + n * 16 + (lane & 15)) * 32 + (lane >> 4) * 8);
#pragma unroll
        for (int m = 0; m < 4; ++m)
#pragma unroll
            for (int n = 0; n < 4; ++n)
                acc[m][n] = __builtin_amdgcn_mfma_f32_16x16x32_bf16(a[m], b[n], acc[m][n], 0, 0, 0);
    }

    const int cr = (lane >> 4) * 4, ccol = lane & 15;
#pragma unroll
    for (int m = 0; m < 4; ++m)
#pragma unroll
        for (int n = 0; n < 4; ++n) {
            const int col = bn + wc * 64 + n * 16 + ccol;
            const float bc = cb[col], gm = gam[col], bt = bet[col];
            const float mv = mu[col], iv = rsqrtf(va[col] + 1e-5f);
#pragma unroll
            for (int j = 0; j < 4; ++j) {
                const int row = bm + wr * 64 + m * 16 + cr + j;
                float x = acc[m][n][j] + bc;
                float y = fmaxf(0.f, gm * (x - mv) * iv + bt);
                xout[(size_t)row * 512 + col] = f2bf(y);
            }
        }
}

// ---------------- fused attention QK^T + row softmax -----------------------
__global__ __launch_bounds__(256) void attn_qksm(
    const unsigned short* __restrict__ q, const unsigned short* __restrict__ k,
    unsigned short* __restrict__ probs)
{
    __shared__ unsigned short As[2048];
    __shared__ unsigned short Bs[8192];
    __shared__ float redm[64][4];
    __shared__ float reds[64][4];
    const int tid = threadIdx.x, wid = tid >> 6, lane = tid & 63;
    const int l15 = lane & 15, bq = lane >> 4;
    const int bm = blockIdx.x * 64;
    const int z = blockIdx.y, b = z >> 2, h = z & 3;

    const unsigned short* A  = q + ((size_t)b * T_) * 512 + h * 128;
    const unsigned short* Bw = k + ((size_t)b * S_) * 512 + h * 128;

    f32x4 acc[4][4];
#pragma unroll
    for (int m = 0; m < 4; ++m)
#pragma unroll
        for (int n = 0; n < 4; ++n) acc[m][n] = (f32x4){0.f, 0.f, 0.f, 0.f};

    const int r0 = wid * 16 + (lane >> 2);
    const int k8 = (lane & 3) * 8;

    for (int k0 = 0; k0 < 128; k0 += 32) {
        __syncthreads();
        gl_lds16(A + (size_t)(bm + r0) * 512 + k0 + k8, As + wid * 512);
        gl_lds16(Bw + (size_t)r0 * 512 + k0 + k8,          Bs + wid * 512);
        gl_lds16(Bw + (size_t)(64 + r0) * 512 + k0 + k8,   Bs + 2048 + wid * 512);
        gl_lds16(Bw + (size_t)(128 + r0) * 512 + k0 + k8,  Bs + 4096 + wid * 512);
        gl_lds16(Bw + (size_t)(192 + r0) * 512 + k0 + k8,  Bs + 6144 + wid * 512);
        __syncthreads();
        bf16x8 a[4], bb[4];
#pragma unroll
        for (int m = 0; m < 4; ++m)
            a[m] = *(const bf16x8*)(As + (m * 16 + l15) * 32 + bq * 8);
#pragma unroll
        for (int n = 0; n < 4; ++n)
            bb[n] = *(const bf16x8*)(Bs + (wid * 64 + n * 16 + l15) * 32 + bq * 8);
#pragma unroll
        for (int m = 0; m < 4; ++m)
#pragma unroll
            for (int n = 0; n < 4; ++n)
                acc[m][n] = __builtin_amdgcn_mfma_f32_16x16x32_bf16(a[m], bb[n], acc[m][n], 0, 0, 0);
    }

    const int cr = (lane >> 4) * 4, ccol = lane & 15;
    const float SC = 0.08838834764831843f;

#pragma unroll
    for (int m = 0; m < 4; ++m)
#pragma unroll
        for (int j = 0; j < 4; ++j) {
            float v = fmaxf(fmaxf(acc[m][0][j], acc[m][1][j]),
                            fmaxf(acc[m][2][j], acc[m][3][j]));
#pragma unroll
            for (int off = 1; off < 16; off <<= 1) v = fmaxf(v, __shfl_xor(v, off));
            if (ccol == 0) redm[m * 16 + cr + j][wid] = v;
        }
    __syncthreads();
#pragma unroll
    for (int m = 0; m < 4; ++m)
#pragma unroll
        for (int j = 0; j < 4; ++j) {
            const int r = m * 16 + cr + j;
            float mx = fmaxf(fmaxf(redm[r][0], redm[r][1]), fmaxf(redm[r][2], redm[r][3]));
            float s = 0.f;
#pragma unroll
            for (int n = 0; n < 4; ++n) {
                float p = __expf((acc[m][n][j] - mx) * SC);
                acc[m][n][j] = p;
                s += p;
            }
#pragma unroll
            for (int off = 1; off < 16; off <<= 1) s += __shfl_xor(s, off);
            if (ccol == 0) reds[r][wid] = s;
        }
    __syncthreads();
#pragma unroll
    for (int m = 0; m < 4; ++m)
#pragma unroll
        for (int j = 0; j < 4; ++j) {
            const int r = m * 16 + cr + j;
            const int row = bm + r;
            if (row >= T_) continue;
            const float inv = 1.f / (reds[r][0] + reds[r][1] + reds[r][2] + reds[r][3]);
#pragma unroll
            for (int n = 0; n < 4; ++n)
                probs[((size_t)z * T_ + row) * 256 + wid * 64 + n * 16 + ccol] =
                    f2bf(acc[m][n][j] * inv);
        }
}

// ---------------- attention PV --------------------------------------------
__global__ __launch_bounds__(256) void attn_pv(
    const unsigned short* __restrict__ probs, const unsigned short* __restrict__ vT,
    unsigned short* __restrict__ ctx)
{
    __shared__ unsigned short As[4096];
    __shared__ unsigned short Bs[4096];
    const int tid = threadIdx.x, w = tid >> 6, lane = tid & 63;
    const int bm = blockIdx.y * 128;
    const int z = blockIdx.z, b = z >> 2, h = z & 3;
    const int wr = w >> 1, wc = w & 1;

    const unsigned short* A  = probs + (size_t)z * T_ * 256;
    const unsigned short* Bw = vT + (size_t)z * 128 * 256;

    f32x4 acc[4][4];
#pragma unroll
    for (int m = 0; m < 4; ++m)
#pragma unroll
        for (int n = 0; n < 4; ++n) acc[m][n] = (f32x4){0.f, 0.f, 0.f, 0.f};

    const int r0 = w * 16 + (lane >> 2);
    const int k8 = (lane & 3) * 8;
    const unsigned short* Ag = A + (size_t)(bm + r0) * 256 + k8;
    const unsigned short* Bg = Bw + (size_t)r0 * 256 + k8;
    unsigned short* Al = As + w * 512;
    unsigned short* Bl = Bs + w * 512;

    for (int k0 = 0; k0 < 256; k0 += 32) {
        __syncthreads();
        gl_lds16(Ag + k0, Al);
        gl_lds16(Ag + (size_t)64 * 256 + k0, Al + 2048);
        gl_lds16(Bg + k0, Bl);
        gl_lds16(Bg + (size_t)64 * 256 + k0, Bl + 2048);
        __syncthreads();
        bf16x8 a[4], bfr[4];
#pragma unroll
        for (int m = 0; m < 4; ++m)
            a[m] = *(const bf16x8*)(As + (wr * 64 + m * 16 + (lane & 15)) * 32 + (lane >> 4) * 8);
#pragma unroll
        for (int n = 0; n < 4; ++n)
            bfr[n] = *(const bf16x8*)(Bs + (wc * 64 + n * 16 + (lane & 15)) * 32 + (lane >> 4) * 8);
#pragma unroll
        for (int m = 0; m < 4; ++m)
#pragma unroll
            for (int n = 0; n < 4; ++n)
                acc[m][n] = __builtin_amdgcn_mfma_f32_16x16x32_bf16(a[m], bfr[n], acc[m][n], 0, 0, 0);
    }

    const int cr = (lane >> 4) * 4, ccol = lane & 15;
#pragma unroll
    for (int m = 0; m < 4; ++m)
#pragma unroll
        for (int n = 0; n < 4; ++n) {
            const int col = wc * 64 + n * 16 + ccol;
#pragma unroll
            for (int j = 0; j < 4; ++j) {
                const int row = bm + wr * 64 + m * 16 + cr + j;
                if (row < T_)
                    ctx[((size_t)b * T_ + row) * 512 + h * 128 + col] = f2bf(acc[m][n][j]);
            }
        }
}

// hist (f16, [dir][b][s][256]) -> enc (bf16, [b][s][512])
__global__ void hist2enc(const _Float16* __restrict__ hist, unsigned short* __restrict__ enc)
{
    int idx = blockIdx.x * 256 + threadIdx.x;
    if (idx >= B_ * S_ * D_) return;
    int d = idx & 511;
    int bs = idx >> 9;
    int b = bs >> 8, s = bs & 255;
    int dir = d >> 8, hid = d & 255;
    enc[idx] = f2bf((float)hist[(((size_t)(dir * 16 + b) * 256 + s) * 256) + hid]);
}

// ---- single fused prologue: weight conversions + embed(bf16) + decin ----
// cWc stored kk-major: cWc[n][kk*512+din] = conv_w[n*2560 + din*5 + kk]
// cWkv = [Wk; Wv] (1024x512); cWm rows 0..79 melW, row 80 stopW, 81..127 zero
__global__ void cvt_all(
    const float* __restrict__ conv_w, const float* __restrict__ Wih_f,
    const float* __restrict__ Wih_b, const float* __restrict__ Wk,
    const float* __restrict__ Wv, const float* __restrict__ Wq,
    const float* __restrict__ Wo, const float* __restrict__ Wih1,
    const float* __restrict__ Wih2, const float* __restrict__ melW,
    const float* __restrict__ stopW,
    const int* __restrict__ txt, const float* __restrict__ emb,
    const float* __restrict__ mel,
    unsigned short* __restrict__ cWc, unsigned short* __restrict__ cWif,
    unsigned short* __restrict__ cWib, unsigned short* __restrict__ cWkv,
    unsigned short* __restrict__ cWq, unsigned short* __restrict__ cWo,
    unsigned short* __restrict__ cW1, unsigned short* __restrict__ cW2,
    unsigned short* __restrict__ cWm,
    unsigned short* __restrict__ xb0, unsigned short* __restrict__ din,
    unsigned short* __restrict__ xcat)
{
    int idx = blockIdx.x * 256 + threadIdx.x;
    if (idx < 3932160) {
        int n = idx / 2560, c = idx - n * 2560;
        int kk = c >> 9, din2 = c & 511;
        cWc[idx] = f2bf(conv_w[(size_t)n * 2560 + din2 * 5 + kk]);
        return;
    }
    idx -= 3932160;
    if (idx < 524288) { cWif[idx] = f2bf(Wih_f[idx]); return; }
    idx -= 524288;
    if (idx < 524288) { cWib[idx] = f2bf(Wih_b[idx]); return; }
    idx -= 524288;
    if (idx < 524288) {
        int r = idx >> 9, k = idx & 511;
        cWkv[idx] = (r < 512) ? f2bf(Wk[(size_t)r * 512 + k])
                              : f2bf(Wv[(size_t)(r - 512) * 512 + k]);
        return;
    }
    idx -= 524288;
    if (idx < 49152) {
        int r = idx / 96, k = idx - r * 96;
        cWq[idx] = (k < 80) ? f2bf(Wq[(size_t)r * 80 + k]) : 0;
        return;
    }
    idx -= 49152;
    if (idx < 262144) { cWo[idx] = f2bf(Wo[idx]); return; }
    idx -= 262144;
    if (idx < 1867776) {
        int n = idx / 608, k = idx - n * 608;
        int orig = (n < 1024) ? n : n + 1024;
        cW1[idx] = (k < 592) ? f2bf(Wih1[(size_t)orig * 592 + k]) : 0;
        return;
    }
    idx -= 1867776;
    if (idx < 3145728) {
        int n = idx >> 10, k = idx & 1023;
        int orig = (n < 1024) ? n : n + 1024;
        cW2[idx] = f2bf(Wih2[(size_t)orig * 1024 + k]);
        return;
    }
    idx -= 3145728;
    if (idx < 131072) {
        int r = idx >> 10, k = idx & 1023;
        cWm[idx] = (r < 80) ? f2bf(melW[(size_t)r * 1024 + k])
                            : (r == 80 ? f2bf(stopW[k]) : 0);
        return;
    }
    idx -= 131072;
    if (idx < B_ * S_ * D_) {   // embedding gather -> bf16
        int bs = idx >> 9, dd = idx & 511;
        xb0[idx] = f2bf(emb[(size_t)txt[bs] * D_ + dd]);
        return;
    }
    idx -= B_ * S_ * D_;
    if (idx < B_ * T_ * 96) {   // decoder input (prev mel frame) + xcat tail
        int r = idx / 96, j = idx - r * 96;
        int b = r / T_, t = r - b * T_;
        float v = (j < M_ && t > 0) ? mel[((size_t)b * T_ + t - 1) * M_ + j] : 0.f;
        unsigned short bv = f2bf(v);
        din[(size_t)r * 96 + j] = bv;
        xcat[(size_t)r * 608 + 512 + j] = bv;
        return;
    }
}

// decoder cell: gates bf16 [rows][3072] = [i;g;o], out bf16; 2 cols/thread
__global__ void dec_cellb2(const unsigned short* __restrict__ g, const float* __restrict__ b,
                           unsigned short* __restrict__ h, int rows)
{
    int idx = blockIdx.x * 256 + threadIdx.x;
    if (idx >= rows * 512) return;
    int r = idx >> 9, j2 = (idx & 511) * 2;
    const unsigned short* gr = g + (size_t)r * 3072;
    ushort2 vi = *(const ushort2*)(gr + j2);
    ushort2 vg = *(const ushort2*)(gr + 1024 + j2);
    ushort2 vo = *(const ushort2*)(gr + 2048 + j2);
    float i0 = sigf(bf2f(vi.x) + b[j2]),          i1 = sigf(bf2f(vi.y) + b[j2 + 1]);
    float g0 = tanhfast(bf2f(vg.x) + b[2048 + j2]), g1 = tanhfast(bf2f(vg.y) + b[2048 + j2 + 1]);
    float o0 = sigf(bf2f(vo.x) + b[3072 + j2]),   o1 = sigf(bf2f(vo.y) + b[3072 + j2 + 1]);
    ushort2 o;
    o.x = f2bf(o0 * tanhfast(i0 * g0));
    o.y = f2bf(o1 * tanhfast(i1 * g1));
    *(ushort2*)(h + (size_t)r * 1024 + j2) = o;
}

// ---------------- persistent LSTM: r7/r11 structure (best: ~690us) ---------
__global__ __launch_bounds__(1024, 4) void lstm_persist9(
    const float* __restrict__ gi_f, const float* __restrict__ gi_b,
    const float* __restrict__ Wf, const float* __restrict__ Wb,
    _Float16* __restrict__ hist,               // [2][16][256][256] f16
    unsigned long long* __restrict__ hstage)   // [2 slot][2 dir][2 half][8 ba][128 hid]
{
    const int blk = blockIdx.x;
    const int dir = blk >> 1, half = blk & 1;
    const float* gi = dir ? gi_b : gi_f;
    const float* W  = dir ? Wb : Wf;
    const int tid = threadIdx.x, wid = tid >> 6, lane = tid & 63;
    const int l15 = lane & 15, q = lane >> 4;
    const int half4 = half * 4, ph4 = (half ^ 1) * 4;

    __shared__ _Float16 h_lds[16][264];
    __shared__ float exch[512][17];

    half8 wOA[4], wPA[4], wOB[4], wPB[4];
    {
        const int gt0 = wid >> 3, hb0 = wid & 7;
        const int gt1 = (wid + 16) >> 3;
        const float* wr0 = W + (size_t)(gt0 * 256 + half * 128 + hb0 * 16 + l15) * 256;
        const float* wr1 = W + (size_t)(gt1 * 256 + half * 128 + hb0 * 16 + l15) * 256;
#pragma unroll
        for (int i = 0; i < 4; ++i) {
            const int kO = (half4 + i) * 32 + q * 8;
            const int kP = (ph4 + i) * 32 + q * 8;
            half8 a, b, c, d;
#pragma unroll
            for (int j = 0; j < 8; ++j) {
                a[j] = (_Float16)wr0[kO + j];
                b[j] = (_Float16)wr0[kP + j];
                c[j] = (_Float16)wr1[kO + j];
                d[j] = (_Float16)wr1[kP + j];
            }
            wOA[i] = a; wPA[i] = b; wOB[i] = c; wPB[i] = d;
        }
    }
    for (int i = tid; i < 16 * 264; i += 1024) ((_Float16*)h_lds)[i] = (_Float16)0.f;
    for (int i = tid; i < 512 * 17; i += 1024) ((float*)exch)[i] = 0.f;

    const int hid = tid & 127;
    const int ba  = tid >> 7;       // 0..7
    const int bb  = ba + 8;
    const int gh  = half * 128 + hid;
    const int pc  = (half ^ 1) * 128 + hid;
    float c0 = 0.f, c1 = 0.f;

    const int exr0 = (wid >> 3) * 128 + (wid & 7) * 16 + l15;
    const int exr1 = ((wid + 16) >> 3) * 128 + (wid & 7) * 16 + l15;

    const int own_base = ((dir * 2 + half) * 8 + ba) * 128 + hid;
    const int par_base = ((dir * 2 + (half ^ 1)) * 8 + ba) * 128 + hid;

    float gp0[4], gp1[4];
    {
        const int s0 = dir ? 255 : 0;
        const float* g0 = gi + ((size_t)s0 * 16 + ba) * 1024 + gh;
        const float* g1 = gi + ((size_t)s0 * 16 + bb) * 1024 + gh;
#pragma unroll
        for (int g2 = 0; g2 < 4; ++g2) { gp0[g2] = g0[g2 * 256]; gp1[g2] = g1[g2 * 256]; }
    }
    __syncthreads();

    for (int step = 0; step < 256; ++step) {
        const int s = dir ? (255 - step) : step;
        const unsigned int tag = (unsigned int)(step + 1);
        const int slot = (step & 1) * 4096;

        float h0, h1;
        {
            float xi = exch[hid][ba] + gp0[0];
            float xf = exch[128 + hid][ba] + gp0[1];
            float xg = exch[256 + hid][ba] + gp0[2];
            float xo = exch[384 + hid][ba] + gp0[3];
            float ig = sigf(xi), fg = sigf(xf), gg = tanhfast(xg), og = sigf(xo);
            c0 = fg * c0 + ig * gg; h0 = og * tanhfast(c0);
            xi = exch[hid][bb] + gp1[0];
            xf = exch[128 + hid][bb] + gp1[1];
            xg = exch[256 + hid][bb] + gp1[2];
            xo = exch[384 + hid][bb] + gp1[3];
            ig = sigf(xi); fg = sigf(xf); gg = tanhfast(xg); og = sigf(xo);
            c1 = fg * c1 + ig * gg; h1 = og * tanhfast(c1);
        }
        {
            unsigned int d32 = (unsigned int)h2u((_Float16)h0) |
                               ((unsigned int)h2u((_Float16)h1) << 16);
            unsigned long long wv = ((unsigned long long)tag << 32) | d32;
            __hip_atomic_store(&hstage[slot + own_base], wv,
                               __ATOMIC_RELAXED, __HIP_MEMORY_SCOPE_AGENT);
        }
        h_lds[ba][gh] = (_Float16)h0;
        h_lds[bb][gh] = (_Float16)h1;
        hist[(((size_t)(dir * 16 + ba) * 256 + s) * 256) + gh] = (_Float16)h0;
        hist[(((size_t)(dir * 16 + bb) * 256 + s) * 256) + gh] = (_Float16)h1;
        if (step < 255) {
            const int s2 = dir ? (254 - step) : (step + 1);
            const float* g0 = gi + ((size_t)s2 * 16 + ba) * 1024 + gh;
            const float* g1 = gi + ((size_t)s2 * 16 + bb) * 1024 + gh;
#pragma unroll
            for (int g2 = 0; g2 < 4; ++g2) { gp0[g2] = g0[g2 * 256]; gp1[g2] = g1[g2 * 256]; }
        }
        __syncthreads();

        if (step < 255) {
            f32x4 acc0 = (f32x4){0.f, 0.f, 0.f, 0.f};
            f32x4 acc1 = (f32x4){0.f, 0.f, 0.f, 0.f};
            const _Float16* hrow = &h_lds[l15][0];
#pragma unroll
            for (int i = 0; i < 4; ++i) {
                half8 a = *(const half8*)(hrow + (half4 + i) * 32 + q * 8);
                acc0 = __builtin_amdgcn_mfma_f32_16x16x32_f16(a, wOA[i], acc0, 0, 0, 0);
                acc1 = __builtin_amdgcn_mfma_f32_16x16x32_f16(a, wOB[i], acc1, 0, 0, 0);
            }
            {
                unsigned long long pv;
                do {
                    pv = __hip_atomic_load(&hstage[slot + par_base],
                                           __ATOMIC_RELAXED, __HIP_MEMORY_SCOPE_AGENT);
                } while ((unsigned int)(pv >> 32) != tag);
                unsigned int d32 = (unsigned int)pv;
                *(unsigned short*)&h_lds[ba][pc] = (unsigned short)(d32 & 0xFFFF);
                *(unsigned short*)&h_lds[bb][pc] = (unsigned short)(d32 >> 16);
            }
            __syncthreads();
#pragma unroll
            for (int i = 0; i < 4; ++i) {
                half8 a = *(const half8*)(hrow + (ph4 + i) * 32 + q * 8);
                acc0 = __builtin_amdgcn_mfma_f32_16x16x32_f16(a, wPA[i], acc0, 0, 0, 0);
                acc1 = __builtin_amdgcn_mfma_f32_16x16x32_f16(a, wPB[i], acc1, 0, 0, 0);
            }
            *(f32x4*)&exch[exr0][q * 4] = acc0;
            *(f32x4*)&exch[exr1][q * 4] = acc1;
            __syncthreads();
        }
    }
}

// ---------------- host orchestration --------------------------------------
static inline void launch_mfma(hipStream_t st, const unsigned short* A, const unsigned short* B,
                               void* C, const float* bias, int M, int N, int K, int ldc,
                               int epi = 0, int aperm = 0, const float* cb = nullptr)
{
    dim3 grid(N / 128, M / 128);
    gemm_mfma<<<grid, 256, 0, st>>>(A, B, C, bias, M, N, K, ldc, epi, aperm, cb);
}

extern "C" void kernel_launch(void* const* d_in, const int* in_sizes, int n_in,
                              void* d_out, int out_size, void* d_ws, size_t ws_size,
                              hipStream_t stream)
{
    const int*   text   = (const int*)d_in[0];
    const float* mel_t  = (const float*)d_in[1];
    const float* emb    = (const float*)d_in[2];
    const float* conv_w = (const float*)d_in[3];
    const float* conv_b = (const float*)d_in[4];
    const float* bn_g   = (const float*)d_in[5];
    const float* bn_b   = (const float*)d_in[6];
    const float* bn_m   = (const float*)d_in[7];
    const float* bn_v   = (const float*)d_in[8];
    const float* Wih_f  = (const float*)d_in[9];
    const float* Whh_f  = (const float*)d_in[10];
    const float* b_f    = (const float*)d_in[11];
    const float* Wih_b  = (const float*)d_in[12];
    const float* Whh_b  = (const float*)d_in[13];
    const float* b_b    = (const float*)d_in[14];
    const float* Wq     = (const float*)d_in[15];
    const float* bq     = (const float*)d_in[16];
    const float* Wk     = (const float*)d_in[17];
    const float* bk     = (const float*)d_in[18];
    const float* Wv     = (const float*)d_in[19];
    const float* bv     = (const float*)d_in[20];
    const float* Wo     = (const float*)d_in[21];
    const float* bo     = (const float*)d_in[22];
    const float* Wih1   = (const float*)d_in[23];
    const float* b1     = (const float*)d_in[24];
    const float* Wih2   = (const float*)d_in[25];
    const float* b2     = (const float*)d_in[26];
    const float* melW   = (const float*)d_in[27];
    const float* melb   = (const float*)d_in[28];
    const float* stopW  = (const float*)d_in[29];
    const float* stopb  = (const float*)d_in[30];
    float* out = (float*)d_out;
    (void)in_sizes; (void)n_in; (void)out_size; (void)ws_size;

    float* ws = (float*)d_ws;
    float* big  = ws;                       // 13107200 f: h2b/h1b region
    float* pool = ws + 13107200;

    unsigned long long* hstage = (unsigned long long*)(ws + 6000000); // 8192 u64 + zbuf
    const unsigned short* zbuf = (const unsigned short*)(hstage + 8192); // 64B zero page

    // phase A/B (encoder)
    float*          gi_f   = pool + 0;
    float*          gi_b   = pool + 4194304;
    unsigned short* enc_bf = (unsigned short*)(pool + 8388608);
    unsigned short* xb0    = (unsigned short*)(pool + 9437184);   // (B*S,512) bf16
    unsigned short* xb1    = (unsigned short*)(pool + 10485760);
    unsigned short* xb2    = (unsigned short*)(pool + 11534336);
    unsigned short* xb3    = (unsigned short*)(pool + 12582912);
    _Float16*       hist   = (_Float16*)(pool + 14155776);        // 4MB f16
    // phase C (attention)
    unsigned short* kbf    = (unsigned short*)(pool + 0);         // 4096x512 (vT = kbf+2097152)
    unsigned short* vT     = (unsigned short*)(pool + 1048576);
    unsigned short* qbf    = (unsigned short*)(pool + 2097152);
    unsigned short* probs  = (unsigned short*)(pool + 9437184);
    unsigned short* dinb   = (unsigned short*)(pool + 16008192);
    unsigned short* ctxb   = (unsigned short*)(pool + 16622592);
    // phase D (decoder)
    unsigned short* gatesb = (unsigned short*)(pool + 0);         // 12800x3072 bf16
    unsigned short* h2b    = (unsigned short*)big;
    unsigned short* h1b    = (unsigned short*)(big + 4000000);
    unsigned short* xcat   = (unsigned short*)(pool + 19899392);
    // weights
    float*          WB     = pool + 23790592;
    unsigned short* cWc  = (unsigned short*)(WB + 0);
    unsigned short* cWif = (unsigned short*)(WB + 1966080);
    unsigned short* cWib = (unsigned short*)(WB + 2228224);
    unsigned short* cWkv = (unsigned short*)(WB + 2490368);   // 1024x512
    unsigned short* cWq  = (unsigned short*)(WB + 2752512);
    unsigned short* cWo  = (unsigned short*)(WB + 2777088);
    unsigned short* cW1  = (unsigned short*)(WB + 2908160);
    unsigned short* cW2  = (unsigned short*)(WB + 3842048);
    unsigned short* cWm  = (unsigned short*)(WB + 5414912);   // 128x1024 (row 80 = stopW)

    auto ceil256 = [](int n) { return (n + 255) / 256; };

    // zero tagged-word staging + conv zero page
    hipMemsetAsync(hstage, 0, 8192 * 8 + 128, stream);

    // ---- fused prologue: weight conversions + embedding(bf16) + dec input ----
    cvt_all<<<ceil256(10960896 + B_ * S_ * D_ + B_ * T_ * 96), 256, 0, stream>>>(
        conv_w, Wih_f, Wih_b, Wk, Wv, Wq, Wo, Wih1, Wih2, melW, stopW,
        text, emb, mel_t,
        cWc, cWif, cWib, cWkv, cWq, cWo, cW1, cW2, cWm,
        xb0, dinb, xcat);

    // ---- encoder: 3 convs (implicit GEMM, no im2col) ----
    {
        dim3 grid(4, 32);
        conv_mfma<<<grid, 256, 0, stream>>>(xb0, cWc,               xb1,
            conv_b, bn_g, bn_b, bn_m, bn_v, zbuf);
        conv_mfma<<<grid, 256, 0, stream>>>(xb1, cWc + 1310720,     xb2,
            conv_b + 512, bn_g + 512, bn_b + 512, bn_m + 512, bn_v + 512, zbuf);
        conv_mfma<<<grid, 256, 0, stream>>>(xb2, cWc + 2621440,     xb3,
            conv_b + 1024, bn_g + 1024, bn_b + 1024, bn_m + 1024, bn_v + 1024, zbuf);
    }

    // ---- encoder LSTM (gi GEMMs read xb3 via row permutation) ----
    launch_mfma(stream, xb3, cWif, gi_f, b_f, S_ * B_, 1024, 512, 1024, 0, 1);
    launch_mfma(stream, xb3, cWib, gi_b, b_b, S_ * B_, 1024, 512, 1024, 0, 1);
    lstm_persist9<<<4, 1024, 0, stream>>>(gi_f, gi_b, Whh_f, Whh_b, hist, hstage);
    hist2enc<<<ceil256(B_ * S_ * D_), 256, 0, stream>>>(hist, enc_bf);

    // ---- attention projections (k+v fused; q) ----
    launch_mfma(stream, enc_bf, cWkv, kbf, bk, B_ * S_, 1024, 512, 512, 5, 0, bv);
    launch_mfma(stream, dinb, cWq, qbf, bq, B_ * T_, 512, 96, 512, 2);

    // ---- attention: fused QK^T+softmax, then PV ----
    attn_qksm<<<dim3(13, 64), 256, 0, stream>>>(qbf, kbf, probs);
    attn_pv<<<dim3(1, 7, 64), 256, 0, stream>>>(probs, vT, ctxb);

    // ---- Wo projection -> xcat[:, 0:512) bf16 ----
    launch_mfma(stream, ctxb, cWo, xcat, bo, B_ * T_, 512, 512, 608, 2);

    // ---- decoder (bf16 gates, f-gate dropped; N=3072=[i;g;o]) ----
    launch_mfma(stream, xcat, cW1, gatesb, nullptr, B_ * T_, 3072, 608, 3072, 2);
    dec_cellb2<<<ceil256(B_ * T_ * 512), 256, 0, stream>>>(gatesb, b1, h1b, B_ * T_);
    launch_mfma(stream, h1b, cW2, gatesb, nullptr, B_ * T_, 3072, 1024, 3072, 2);
    dec_cellb2<<<ceil256(B_ * T_ * 512), 256, 0, stream>>>(gatesb, b2, h2b, B_ * T_);

    // ---- output heads: mel + stop in ONE GEMM (stop = col 80 of cWm) ----
    launch_mfma(stream, h2b, cWm, out, melb, B_ * T_, 128, 1024, 80, 4, 0, stopb);
}

// Round 15
// 1331.869 us; speedup vs baseline: 1.3239x; 1.0011x over previous
//
#include <hip/hip_runtime.h>
#include <hip/hip_bf16.h>
#include <math.h>

#define B_ 16
#define S_ 256
#define T_ 800
#define V_ 256
#define D_ 512
#define M_ 80
#define H_ 1024
#define NH_ 4
#define HD_ 128
#define EH_ 256

using bf16x8 = __attribute__((ext_vector_type(8))) short;
using f32x4  = __attribute__((ext_vector_type(4))) float;
typedef _Float16 half8 __attribute__((ext_vector_type(8)));

__device__ __forceinline__ float sigf(float x) { return 1.f / (1.f + __expf(-x)); }
__device__ __forceinline__ float tanhfast(float x) {
    float e = __expf(2.f * x);
    return 1.f - 2.f / (e + 1.f);
}

__device__ __forceinline__ unsigned short f2bf(float f) {
    unsigned int u = __float_as_uint(f);
    unsigned int r = (u + 0x7FFFu + ((u >> 16) & 1u)) >> 16;
    return (unsigned short)r;
}
__device__ __forceinline__ float bf2f(unsigned short u) {
    return __uint_as_float(((unsigned int)u) << 16);
}
__device__ __forceinline__ unsigned short h2u(_Float16 x) {
    union { _Float16 f; unsigned short u; } c; c.f = x; return c.u;
}

__device__ __forceinline__ void gl_lds16(const unsigned short* g, unsigned short* l) {
    __builtin_amdgcn_global_load_lds((const __attribute__((address_space(1))) void*)g,
                                     (__attribute__((address_space(3))) void*)l, 16, 0, 0);
}

// ---------------- MFMA bf16 GEMM: C = A(M,K) @ B(N,K)^T --------------------
// epi: 0 fp32(+bias), 2 bf16(+bias), 4 mel+stop fused, 5 kv fused,
//      6 merged-gi fp32 (bias=b_f col<1024, cb=b_b col>=1024)
// aperm: 0 none; 1 row perm r->(r&15)*256+(r>>4); 2 hist layout
//        (row stride 256, k-chunk offset +1048576 when k0>=256)
// swz: XCD-aware bijective blockId swizzle (requires nwg%8==0)
__global__ __launch_bounds__(256) void gemm_mfma(
    const unsigned short* __restrict__ A, const unsigned short* __restrict__ Bw,
    void* __restrict__ Cv, const float* __restrict__ bias,
    int M, int N, int K, int ldc, int epi, int aperm, int swz,
    const float* __restrict__ cb)
{
    __shared__ unsigned short As[4096];
    __shared__ unsigned short Bs[4096];
    const int tid = threadIdx.x, w = tid >> 6, lane = tid & 63;
    int bx = blockIdx.x, by = blockIdx.y;
    if (swz) {
        const int nwg = gridDim.x * gridDim.y;
        const int id = by * gridDim.x + bx;
        const int nid = (id & 7) * (nwg >> 3) + (id >> 3);
        bx = nid % gridDim.x; by = nid / gridDim.x;
    }
    const int bm = by * 128, bn = bx * 128;
    const int wr = w >> 1, wc = w & 1;

    f32x4 acc[4][4];
#pragma unroll
    for (int m = 0; m < 4; ++m)
#pragma unroll
        for (int n = 0; n < 4; ++n) acc[m][n] = (f32x4){0.f, 0.f, 0.f, 0.f};

    const int r0 = w * 16 + (lane >> 2);
    const int k8 = (lane & 3) * 8;
    int ar0 = bm + r0, ar1 = bm + r0 + 64;
    if (aperm == 1) {
        ar0 = ((ar0 & 15) << 8) | (ar0 >> 4);
        ar1 = ((ar1 & 15) << 8) | (ar1 >> 4);
    }
    const size_t astr = (aperm == 2) ? 256 : (size_t)K;
    const unsigned short* Ag0 = A + (size_t)ar0 * astr + k8;
    const unsigned short* Ag1 = A + (size_t)ar1 * astr + k8;
    const unsigned short* Bg = Bw + (size_t)(bn + r0) * K + k8;
    unsigned short* Al = As + w * 512;
    unsigned short* Bl = Bs + w * 512;

    for (int k0 = 0; k0 < K; k0 += 32) {
        const int kA = (aperm == 2) ? ((k0 & 255) + ((k0 >> 8) << 20)) : k0;
        __syncthreads();
        gl_lds16(Ag0 + kA, Al);
        gl_lds16(Ag1 + kA, Al + 2048);
        gl_lds16(Bg + k0, Bl);
        gl_lds16(Bg + (size_t)64 * K + k0, Bl + 2048);
        __syncthreads();
        bf16x8 a[4], b[4];
#pragma unroll
        for (int m = 0; m < 4; ++m)
            a[m] = *(const bf16x8*)(As + (wr * 64 + m * 16 + (lane & 15)) * 32 + (lane >> 4) * 8);
#pragma unroll
        for (int n = 0; n < 4; ++n)
            b[n] = *(const bf16x8*)(Bs + (wc * 64 + n * 16 + (lane & 15)) * 32 + (lane >> 4) * 8);
#pragma unroll
        for (int m = 0; m < 4; ++m)
#pragma unroll
            for (int n = 0; n < 4; ++n)
                acc[m][n] = __builtin_amdgcn_mfma_f32_16x16x32_bf16(a[m], b[n], acc[m][n], 0, 0, 0);
    }

    const int cr = (lane >> 4) * 4, ccol = lane & 15;
#pragma unroll
    for (int m = 0; m < 4; ++m)
#pragma unroll
        for (int n = 0; n < 4; ++n) {
            const int col = bn + wc * 64 + n * 16 + ccol;
            float bv;
            if (epi == 5)      bv = (col < 512) ? bias[col] : cb[col - 512];
            else if (epi == 6) bv = (col < 1024) ? bias[col] : cb[col - 1024];
            else if (epi == 4) bv = (col < 80) ? bias[col] : (col == 80 ? cb[0] : 0.f);
            else               bv = bias ? bias[col] : 0.f;
#pragma unroll
            for (int j = 0; j < 4; ++j) {
                const int row = bm + wr * 64 + m * 16 + cr + j;
                float v = acc[m][n][j] + bv;
                if (epi == 2) {
                    ((unsigned short*)Cv)[(size_t)row * ldc + col] = f2bf(v);
                } else if (epi == 5) {
                    if (col < 512) {
                        ((unsigned short*)Cv)[(size_t)row * 512 + col] = f2bf(v);
                    } else {
                        unsigned short* vTo = (unsigned short*)Cv + 2097152;
                        const int c2 = col - 512, hh = c2 >> 7, dd = c2 & 127;
                        const int bb2 = row >> 8, ss = row & 255;
                        vTo[((size_t)(bb2 * 4 + hh) * 128 + dd) * 256 + ss] = f2bf(v);
                    }
                } else if (epi == 4) {
                    if (col < 80)       ((float*)Cv)[(size_t)row * ldc + col] = v;
                    else if (col == 80) ((float*)Cv)[1024000 + row] = v;
                } else {
                    ((float*)Cv)[(size_t)row * ldc + col] = v;
                }
            }
        }
}

// ---------------- conv layer as implicit GEMM (kk-major weights) -----------
__global__ __launch_bounds__(256) void conv_mfma(
    const unsigned short* __restrict__ xin, const unsigned short* __restrict__ Bw,
    unsigned short* __restrict__ xout,
    const float* __restrict__ cb, const float* __restrict__ gam,
    const float* __restrict__ bet, const float* __restrict__ mu,
    const float* __restrict__ va, const unsigned short* __restrict__ zbuf)
{
    __shared__ unsigned short As[4096];
    __shared__ unsigned short Bs[4096];
    const int tid = threadIdx.x, w = tid >> 6, lane = tid & 63;
    const int bm = blockIdx.y * 128, bn = blockIdx.x * 128;
    const int wr = w >> 1, wc = w & 1;

    f32x4 acc[4][4];
#pragma unroll
    for (int m = 0; m < 4; ++m)
#pragma unroll
        for (int n = 0; n < 4; ++n) acc[m][n] = (f32x4){0.f, 0.f, 0.f, 0.f};

    const int r0 = w * 16 + (lane >> 2);
    const int k8 = (lane & 3) * 8;
    const int gr0 = bm + r0, gr1 = bm + r0 + 64;
    const int b0 = gr0 >> 8, s0 = gr0 & 255;
    const int b1 = gr1 >> 8, s1 = gr1 & 255;
    const unsigned short* Bg = Bw + (size_t)(bn + r0) * 2560 + k8;
    unsigned short* Al = As + w * 512;
    unsigned short* Bl = Bs + w * 512;

    for (int k0 = 0; k0 < 2560; k0 += 32) {
        const int kk = k0 >> 9;
        const int d0 = k0 & 511;
        const int s2a = s0 + kk - 2;
        const int s2b = s1 + kk - 2;
        const unsigned short* pa = (s2a >= 0 && s2a < 256)
            ? xin + ((size_t)(b0 * 256 + s2a) * 512 + d0 + k8) : zbuf;
        const unsigned short* pb = (s2b >= 0 && s2b < 256)
            ? xin + ((size_t)(b1 * 256 + s2b) * 512 + d0 + k8) : zbuf;
        __syncthreads();
        gl_lds16(pa, Al);
        gl_lds16(pb, Al + 2048);
        gl_lds16(Bg + k0, Bl);
        gl_lds16(Bg + (size_t)64 * 2560 + k0, Bl + 2048);
        __syncthreads();
        bf16x8 a[4], b[4];
#pragma unroll
        for (int m = 0; m < 4; ++m)
            a[m] = *(const bf16x8*)(As + (wr * 64 + m * 16 + (lane & 15)) * 32 + (lane >> 4) * 8);
#pragma unroll
        for (int n = 0; n < 4; ++n)
            b[n] = *(const bf16x8*)(Bs + (wc * 64 + n * 16 + (lane & 15)) * 32 + (lane >> 4) * 8);
#pragma unroll
        for (int m = 0; m < 4; ++m)
#pragma unroll
            for (int n = 0; n < 4; ++n)
                acc[m][n] = __builtin_amdgcn_mfma_f32_16x16x32_bf16(a[m], b[n], acc[m][n], 0, 0, 0);
    }

    const int cr = (lane >> 4) * 4, ccol = lane & 15;
#pragma unroll
    for (int m = 0; m < 4; ++m)
#pragma unroll
        for (int n = 0; n < 4; ++n) {
            const int col = bn + wc * 64 + n * 16 + ccol;
            const float bc = cb[col], gm = gam[col], bt = bet[col];
            const float mv = mu[col], iv = rsqrtf(va[col] + 1e-5f);
#pragma unroll
            for (int j = 0; j < 4; ++j) {
                const int row = bm + wr * 64 + m * 16 + cr + j;
                float x = acc[m][n][j] + bc;
                float y = fmaxf(0.f, gm * (x - mv) * iv + bt);
                xout[(size_t)row * 512 + col] = f2bf(y);
            }
        }
}

// ---------------- fused attention QK^T + row softmax -----------------------
__global__ __launch_bounds__(256) void attn_qksm(
    const unsigned short* __restrict__ q, const unsigned short* __restrict__ k,
    unsigned short* __restrict__ probs)
{
    __shared__ unsigned short As[2048];
    __shared__ unsigned short Bs[8192];
    __shared__ float redm[64][4];
    __shared__ float reds[64][4];
    const int tid = threadIdx.x, wid = tid >> 6, lane = tid & 63;
    const int l15 = lane & 15, bq = lane >> 4;
    const int bm = blockIdx.x * 64;
    const int z = blockIdx.y, b = z >> 2, h = z & 3;

    const unsigned short* A  = q + ((size_t)b * T_) * 512 + h * 128;
    const unsigned short* Bw = k + ((size_t)b * S_) * 512 + h * 128;

    f32x4 acc[4][4];
#pragma unroll
    for (int m = 0; m < 4; ++m)
#pragma unroll
        for (int n = 0; n < 4; ++n) acc[m][n] = (f32x4){0.f, 0.f, 0.f, 0.f};

    const int r0 = wid * 16 + (lane >> 2);
    const int k8 = (lane & 3) * 8;

    for (int k0 = 0; k0 < 128; k0 += 32) {
        __syncthreads();
        gl_lds16(A + (size_t)(bm + r0) * 512 + k0 + k8, As + wid * 512);
        gl_lds16(Bw + (size_t)r0 * 512 + k0 + k8,          Bs + wid * 512);
        gl_lds16(Bw + (size_t)(64 + r0) * 512 + k0 + k8,   Bs + 2048 + wid * 512);
        gl_lds16(Bw + (size_t)(128 + r0) * 512 + k0 + k8,  Bs + 4096 + wid * 512);
        gl_lds16(Bw + (size_t)(192 + r0) * 512 + k0 + k8,  Bs + 6144 + wid * 512);
        __syncthreads();
        bf16x8 a[4], bb[4];
#pragma unroll
        for (int m = 0; m < 4; ++m)
            a[m] = *(const bf16x8*)(As + (m * 16 + l15) * 32 + bq * 8);
#pragma unroll
        for (int n = 0; n < 4; ++n)
            bb[n] = *(const bf16x8*)(Bs + (wid * 64 + n * 16 + l15) * 32 + bq * 8);
#pragma unroll
        for (int m = 0; m < 4; ++m)
#pragma unroll
            for (int n = 0; n < 4; ++n)
                acc[m][n] = __builtin_amdgcn_mfma_f32_16x16x32_bf16(a[m], bb[n], acc[m][n], 0, 0, 0);
    }

    const int cr = (lane >> 4) * 4, ccol = lane & 15;
    const float SC = 0.08838834764831843f;

#pragma unroll
    for (int m = 0; m < 4; ++m)
#pragma unroll
        for (int j = 0; j < 4; ++j) {
            float v = fmaxf(fmaxf(acc[m][0][j], acc[m][1][j]),
                            fmaxf(acc[m][2][j], acc[m][3][j]));
#pragma unroll
            for (int off = 1; off < 16; off <<= 1) v = fmaxf(v, __shfl_xor(v, off));
            if (ccol == 0) redm[m * 16 + cr + j][wid] = v;
        }
    __syncthreads();
#pragma unroll
    for (int m = 0; m < 4; ++m)
#pragma unroll
        for (int j = 0; j < 4; ++j) {
            const int r = m * 16 + cr + j;
            float mx = fmaxf(fmaxf(redm[r][0], redm[r][1]), fmaxf(redm[r][2], redm[r][3]));
            float s = 0.f;
#pragma unroll
            for (int n = 0; n < 4; ++n) {
                float p = __expf((acc[m][n][j] - mx) * SC);
                acc[m][n][j] = p;
                s += p;
            }
#pragma unroll
            for (int off = 1; off < 16; off <<= 1) s += __shfl_xor(s, off);
            if (ccol == 0) reds[r][wid] = s;
        }
    __syncthreads();
#pragma unroll
    for (int m = 0; m < 4; ++m)
#pragma unroll
        for (int j = 0; j < 4; ++j) {
            const int r = m * 16 + cr + j;
            const int row = bm + r;
            if (row >= T_) continue;
            const float inv = 1.f / (reds[r][0] + reds[r][1] + reds[r][2] + reds[r][3]);
#pragma unroll
            for (int n = 0; n < 4; ++n)
                probs[((size_t)z * T_ + row) * 256 + wid * 64 + n * 16 + ccol] =
                    f2bf(acc[m][n][j] * inv);
        }
}

// ---------------- attention PV --------------------------------------------
__global__ __launch_bounds__(256) void attn_pv(
    const unsigned short* __restrict__ probs, const unsigned short* __restrict__ vT,
    unsigned short* __restrict__ ctx)
{
    __shared__ unsigned short As[4096];
    __shared__ unsigned short Bs[4096];
    const int tid = threadIdx.x, w = tid >> 6, lane = tid & 63;
    const int bm = blockIdx.y * 128;
    const int z = blockIdx.z, b = z >> 2, h = z & 3;
    const int wr = w >> 1, wc = w & 1;

    const unsigned short* A  = probs + (size_t)z * T_ * 256;
    const unsigned short* Bw = vT + (size_t)z * 128 * 256;

    f32x4 acc[4][4];
#pragma unroll
    for (int m = 0; m < 4; ++m)
#pragma unroll
        for (int n = 0; n < 4; ++n) acc[m][n] = (f32x4){0.f, 0.f, 0.f, 0.f};

    const int r0 = w * 16 + (lane >> 2);
    const int k8 = (lane & 3) * 8;
    const unsigned short* Ag = A + (size_t)(bm + r0) * 256 + k8;
    const unsigned short* Bg = Bw + (size_t)r0 * 256 + k8;
    unsigned short* Al = As + w * 512;
    unsigned short* Bl = Bs + w * 512;

    for (int k0 = 0; k0 < 256; k0 += 32) {
        __syncthreads();
        gl_lds16(Ag + k0, Al);
        gl_lds16(Ag + (size_t)64 * 256 + k0, Al + 2048);
        gl_lds16(Bg + k0, Bl);
        gl_lds16(Bg + (size_t)64 * 256 + k0, Bl + 2048);
        __syncthreads();
        bf16x8 a[4], bfr[4];
#pragma unroll
        for (int m = 0; m < 4; ++m)
            a[m] = *(const bf16x8*)(As + (wr * 64 + m * 16 + (lane & 15)) * 32 + (lane >> 4) * 8);
#pragma unroll
        for (int n = 0; n < 4; ++n)
            bfr[n] = *(const bf16x8*)(Bs + (wc * 64 + n * 16 + (lane & 15)) * 32 + (lane >> 4) * 8);
#pragma unroll
        for (int m = 0; m < 4; ++m)
#pragma unroll
            for (int n = 0; n < 4; ++n)
                acc[m][n] = __builtin_amdgcn_mfma_f32_16x16x32_bf16(a[m], bfr[n], acc[m][n], 0, 0, 0);
    }

    const int cr = (lane >> 4) * 4, ccol = lane & 15;
#pragma unroll
    for (int m = 0; m < 4; ++m)
#pragma unroll
        for (int n = 0; n < 4; ++n) {
            const int col = wc * 64 + n * 16 + ccol;
#pragma unroll
            for (int j = 0; j < 4; ++j) {
                const int row = bm + wr * 64 + m * 16 + cr + j;
                if (row < T_)
                    ctx[((size_t)b * T_ + row) * 512 + h * 128 + col] = f2bf(acc[m][n][j]);
            }
        }
}

// ---- single fused prologue: weight conversions + embed(bf16) + decin ----
__global__ void cvt_all(
    const float* __restrict__ conv_w, const float* __restrict__ Wih_f,
    const float* __restrict__ Wih_b, const float* __restrict__ Wk,
    const float* __restrict__ Wv, const float* __restrict__ Wq,
    const float* __restrict__ Wo, const float* __restrict__ Wih1,
    const float* __restrict__ Wih2, const float* __restrict__ melW,
    const float* __restrict__ stopW,
    const int* __restrict__ txt, const float* __restrict__ emb,
    const float* __restrict__ mel,
    unsigned short* __restrict__ cWc, unsigned short* __restrict__ cWif,
    unsigned short* __restrict__ cWib, unsigned short* __restrict__ cWkv,
    unsigned short* __restrict__ cWq, unsigned short* __restrict__ cWo,
    unsigned short* __restrict__ cW1, unsigned short* __restrict__ cW2,
    unsigned short* __restrict__ cWm,
    unsigned short* __restrict__ xb0, unsigned short* __restrict__ din,
    unsigned short* __restrict__ xcat)
{
    int idx = blockIdx.x * 256 + threadIdx.x;
    if (idx < 3932160) {
        int n = idx / 2560, c = idx - n * 2560;
        int kk = c >> 9, din2 = c & 511;
        cWc[idx] = f2bf(conv_w[(size_t)n * 2560 + din2 * 5 + kk]);
        return;
    }
    idx -= 3932160;
    if (idx < 524288) { cWif[idx] = f2bf(Wih_f[idx]); return; }
    idx -= 524288;
    if (idx < 524288) { cWib[idx] = f2bf(Wih_b[idx]); return; }
    idx -= 524288;
    if (idx < 524288) {
        int r = idx >> 9, k = idx & 511;
        cWkv[idx] = (r < 512) ? f2bf(Wk[(size_t)r * 512 + k])
                              : f2bf(Wv[(size_t)(r - 512) * 512 + k]);
        return;
    }
    idx -= 524288;
    if (idx < 49152) {
        int r = idx / 96, k = idx - r * 96;
        cWq[idx] = (k < 80) ? f2bf(Wq[(size_t)r * 80 + k]) : 0;
        return;
    }
    idx -= 49152;
    if (idx < 262144) { cWo[idx] = f2bf(Wo[idx]); return; }
    idx -= 262144;
    if (idx < 1867776) {
        int n = idx / 608, k = idx - n * 608;
        int orig = (n < 1024) ? n : n + 1024;
        cW1[idx] = (k < 592) ? f2bf(Wih1[(size_t)orig * 592 + k]) : 0;
        return;
    }
    idx -= 1867776;
    if (idx < 3145728) {
        int n = idx >> 10, k = idx & 1023;
        int orig = (n < 1024) ? n : n + 1024;
        cW2[idx] = f2bf(Wih2[(size_t)orig * 1024 + k]);
        return;
    }
    idx -= 3145728;
    if (idx < 131072) {
        int r = idx >> 10, k = idx & 1023;
        cWm[idx] = (r < 80) ? f2bf(melW[(size_t)r * 1024 + k])
                            : (r == 80 ? f2bf(stopW[k]) : 0);
        return;
    }
    idx -= 131072;
    if (idx < B_ * S_ * D_) {
        int bs = idx >> 9, dd = idx & 511;
        xb0[idx] = f2bf(emb[(size_t)txt[bs] * D_ + dd]);
        return;
    }
    idx -= B_ * S_ * D_;
    if (idx < B_ * T_ * 96) {
        int r = idx / 96, j = idx - r * 96;
        int b = r / T_, t = r - b * T_;
        float v = (j < M_ && t > 0) ? mel[((size_t)b * T_ + t - 1) * M_ + j] : 0.f;
        unsigned short bv = f2bf(v);
        din[(size_t)r * 96 + j] = bv;
        xcat[(size_t)r * 608 + 512 + j] = bv;
        return;
    }
}

// decoder cell: gates bf16 [rows][3072] = [i;g;o], out bf16; 2 cols/thread
__global__ void dec_cellb2(const unsigned short* __restrict__ g, const float* __restrict__ b,
                           unsigned short* __restrict__ h, int rows)
{
    int idx = blockIdx.x * 256 + threadIdx.x;
    if (idx >= rows * 512) return;
    int r = idx >> 9, j2 = (idx & 511) * 2;
    const unsigned short* gr = g + (size_t)r * 3072;
    ushort2 vi = *(const ushort2*)(gr + j2);
    ushort2 vg = *(const ushort2*)(gr + 1024 + j2);
    ushort2 vo = *(const ushort2*)(gr + 2048 + j2);
    float i0 = sigf(bf2f(vi.x) + b[j2]),          i1 = sigf(bf2f(vi.y) + b[j2 + 1]);
    float g0 = tanhfast(bf2f(vg.x) + b[2048 + j2]), g1 = tanhfast(bf2f(vg.y) + b[2048 + j2 + 1]);
    float o0 = sigf(bf2f(vo.x) + b[3072 + j2]),   o1 = sigf(bf2f(vo.y) + b[3072 + j2 + 1]);
    ushort2 o;
    o.x = f2bf(o0 * tanhfast(i0 * g0));
    o.y = f2bf(o1 * tanhfast(i1 * g1));
    *(ushort2*)(h + (size_t)r * 1024 + j2) = o;
}

// ---------------- persistent LSTM (r7/r11 structure; gi stride 2048;
//                  hist stored bf16, read in-place by the kv GEMM) ----------
__global__ __launch_bounds__(1024, 4) void lstm_persist9(
    const float* __restrict__ gi_f, const float* __restrict__ gi_b,
    const float* __restrict__ Wf, const float* __restrict__ Wb,
    unsigned short* __restrict__ hist,         // [2][16][256][256] bf16
    unsigned long long* __restrict__ hstage)   // [2 slot][2 dir][2 half][8 ba][128 hid]
{
    const int blk = blockIdx.x;
    const int dir = blk >> 1, half = blk & 1;
    const float* gi = dir ? gi_b : gi_f;
    const float* W  = dir ? Wb : Wf;
    const int tid = threadIdx.x, wid = tid >> 6, lane = tid & 63;
    const int l15 = lane & 15, q = lane >> 4;
    const int half4 = half * 4, ph4 = (half ^ 1) * 4;

    __shared__ _Float16 h_lds[16][264];
    __shared__ float exch[512][17];

    half8 wOA[4], wPA[4], wOB[4], wPB[4];
    {
        const int gt0 = wid >> 3, hb0 = wid & 7;
        const int gt1 = (wid + 16) >> 3;
        const float* wr0 = W + (size_t)(gt0 * 256 + half * 128 + hb0 * 16 + l15) * 256;
        const float* wr1 = W + (size_t)(gt1 * 256 + half * 128 + hb0 * 16 + l15) * 256;
#pragma unroll
        for (int i = 0; i < 4; ++i) {
            const int kO = (half4 + i) * 32 + q * 8;
            const int kP = (ph4 + i) * 32 + q * 8;
            half8 a, b, c, d;
#pragma unroll
            for (int j = 0; j < 8; ++j) {
                a[j] = (_Float16)wr0[kO + j];
                b[j] = (_Float16)wr0[kP + j];
                c[j] = (_Float16)wr1[kO + j];
                d[j] = (_Float16)wr1[kP + j];
            }
            wOA[i] = a; wPA[i] = b; wOB[i] = c; wPB[i] = d;
        }
    }
    for (int i = tid; i < 16 * 264; i += 1024) ((_Float16*)h_lds)[i] = (_Float16)0.f;
    for (int i = tid; i < 512 * 17; i += 1024) ((float*)exch)[i] = 0.f;

    const int hid = tid & 127;
    const int ba  = tid >> 7;       // 0..7
    const int bb  = ba + 8;
    const int gh  = half * 128 + hid;
    const int pc  = (half ^ 1) * 128 + hid;
    float c0 = 0.f, c1 = 0.f;

    const int exr0 = (wid >> 3) * 128 + (wid & 7) * 16 + l15;
    const int exr1 = ((wid + 16) >> 3) * 128 + (wid & 7) * 16 + l15;

    const int own_base = ((dir * 2 + half) * 8 + ba) * 128 + hid;
    const int par_base = ((dir * 2 + (half ^ 1)) * 8 + ba) * 128 + hid;

    float gp0[4], gp1[4];
    {
        const int s0 = dir ? 255 : 0;
        const float* g0 = gi + ((size_t)s0 * 16 + ba) * 2048 + gh;
        const float* g1 = gi + ((size_t)s0 * 16 + bb) * 2048 + gh;
#pragma unroll
        for (int g2 = 0; g2 < 4; ++g2) { gp0[g2] = g0[g2 * 256]; gp1[g2] = g1[g2 * 256]; }
    }
    __syncthreads();

    for (int step = 0; step < 256; ++step) {
        const int s = dir ? (255 - step) : step;
        const unsigned int tag = (unsigned int)(step + 1);
        const int slot = (step & 1) * 4096;

        float h0, h1;
        {
            float xi = exch[hid][ba] + gp0[0];
            float xf = exch[128 + hid][ba] + gp0[1];
            float xg = exch[256 + hid][ba] + gp0[2];
            float xo = exch[384 + hid][ba] + gp0[3];
            float ig = sigf(xi), fg = sigf(xf), gg = tanhfast(xg), og = sigf(xo);
            c0 = fg * c0 + ig * gg; h0 = og * tanhfast(c0);
            xi = exch[hid][bb] + gp1[0];
            xf = exch[128 + hid][bb] + gp1[1];
            xg = exch[256 + hid][bb] + gp1[2];
            xo = exch[384 + hid][bb] + gp1[3];
            ig = sigf(xi); fg = sigf(xf); gg = tanhfast(xg); og = sigf(xo);
            c1 = fg * c1 + ig * gg; h1 = og * tanhfast(c1);
        }
        {
            unsigned int d32 = (unsigned int)h2u((_Float16)h0) |
                               ((unsigned int)h2u((_Float16)h1) << 16);
            unsigned long long wv = ((unsigned long long)tag << 32) | d32;
            __hip_atomic_store(&hstage[slot + own_base], wv,
                               __ATOMIC_RELAXED, __HIP_MEMORY_SCOPE_AGENT);
        }
        h_lds[ba][gh] = (_Float16)h0;
        h_lds[bb][gh] = (_Float16)h1;
        hist[(((size_t)(dir * 16 + ba) * 256 + s) * 256) + gh] = f2bf(h0);
        hist[(((size_t)(dir * 16 + bb) * 256 + s) * 256) + gh] = f2bf(h1);
        if (step < 255) {
            const int s2 = dir ? (254 - step) : (step + 1);
            const float* g0 = gi + ((size_t)s2 * 16 + ba) * 2048 + gh;
            const float* g1 = gi + ((size_t)s2 * 16 + bb) * 2048 + gh;
#pragma unroll
            for (int g2 = 0; g2 < 4; ++g2) { gp0[g2] = g0[g2 * 256]; gp1[g2] = g1[g2 * 256]; }
        }
        __syncthreads();

        if (step < 255) {
            f32x4 acc0 = (f32x4){0.f, 0.f, 0.f, 0.f};
            f32x4 acc1 = (f32x4){0.f, 0.f, 0.f, 0.f};
            const _Float16* hrow = &h_lds[l15][0];
#pragma unroll
            for (int i = 0; i < 4; ++i) {
                half8 a = *(const half8*)(hrow + (half4 + i) * 32 + q * 8);
                acc0 = __builtin_amdgcn_mfma_f32_16x16x32_f16(a, wOA[i], acc0, 0, 0, 0);
                acc1 = __builtin_amdgcn_mfma_f32_16x16x32_f16(a, wOB[i], acc1, 0, 0, 0);
            }
            {
                unsigned long long pv;
                do {
                    pv = __hip_atomic_load(&hstage[slot + par_base],
                                           __ATOMIC_RELAXED, __HIP_MEMORY_SCOPE_AGENT);
                } while ((unsigned int)(pv >> 32) != tag);
                unsigned int d32 = (unsigned int)pv;
                *(unsigned short*)&h_lds[ba][pc] = (unsigned short)(d32 & 0xFFFF);
                *(unsigned short*)&h_lds[bb][pc] = (unsigned short)(d32 >> 16);
            }
            __syncthreads();
#pragma unroll
            for (int i = 0; i < 4; ++i) {
                half8 a = *(const half8*)(hrow + (ph4 + i) * 32 + q * 8);
                acc0 = __builtin_amdgcn_mfma_f32_16x16x32_f16(a, wPA[i], acc0, 0, 0, 0);
                acc1 = __builtin_amdgcn_mfma_f32_16x16x32_f16(a, wPB[i], acc1, 0, 0, 0);
            }
            *(f32x4*)&exch[exr0][q * 4] = acc0;
            *(f32x4*)&exch[exr1][q * 4] = acc1;
            __syncthreads();
        }
    }
}

// ---------------- host orchestration --------------------------------------
static inline void launch_mfma(hipStream_t st, const unsigned short* A, const unsigned short* B,
                               void* C, const float* bias, int M, int N, int K, int ldc,
                               int epi = 0, int aperm = 0, const float* cb = nullptr,
                               int swz = 0)
{
    dim3 grid(N / 128, M / 128);
    gemm_mfma<<<grid, 256, 0, st>>>(A, B, C, bias, M, N, K, ldc, epi, aperm, swz, cb);
}

extern "C" void kernel_launch(void* const* d_in, const int* in_sizes, int n_in,
                              void* d_out, int out_size, void* d_ws, size_t ws_size,
                              hipStream_t stream)
{
    const int*   text   = (const int*)d_in[0];
    const float* mel_t  = (const float*)d_in[1];
    const float* emb    = (const float*)d_in[2];
    const float* conv_w = (const float*)d_in[3];
    const float* conv_b = (const float*)d_in[4];
    const float* bn_g   = (const float*)d_in[5];
    const float* bn_b   = (const float*)d_in[6];
    const float* bn_m   = (const float*)d_in[7];
    const float* bn_v   = (const float*)d_in[8];
    const float* Wih_f  = (const float*)d_in[9];
    const float* Whh_f  = (const float*)d_in[10];
    const float* b_f    = (const float*)d_in[11];
    const float* Wih_b  = (const float*)d_in[12];
    const float* Whh_b  = (const float*)d_in[13];
    const float* b_b    = (const float*)d_in[14];
    const float* Wq     = (const float*)d_in[15];
    const float* bq     = (const float*)d_in[16];
    const float* Wk     = (const float*)d_in[17];
    const float* bk     = (const float*)d_in[18];
    const float* Wv     = (const float*)d_in[19];
    const float* bv     = (const float*)d_in[20];
    const float* Wo     = (const float*)d_in[21];
    const float* bo     = (const float*)d_in[22];
    const float* Wih1   = (const float*)d_in[23];
    const float* b1     = (const float*)d_in[24];
    const float* Wih2   = (const float*)d_in[25];
    const float* b2     = (const float*)d_in[26];
    const float* melW   = (const float*)d_in[27];
    const float* melb   = (const float*)d_in[28];
    const float* stopW  = (const float*)d_in[29];
    const float* stopb  = (const float*)d_in[30];
    float* out = (float*)d_out;
    (void)in_sizes; (void)n_in; (void)out_size; (void)ws_size;

    float* ws = (float*)d_ws;
    float* big  = ws;                       // h2b/h1b region
    float* pool = ws + 13107200;

    unsigned long long* hstage = (unsigned long long*)(ws + 6000000); // 8192 u64 + zbuf
    const unsigned short* zbuf = (const unsigned short*)(hstage + 8192);

    // phase A/B (encoder)
    float*          gibuf  = pool + 0;                            // [4096][2048] f32
    float*          gi_f   = gibuf;
    float*          gi_b   = gibuf + 1024;
    unsigned short* xb0    = (unsigned short*)(pool + 9437184);   // (B*S,512) bf16
    unsigned short* xb1    = (unsigned short*)(pool + 10485760);
    unsigned short* xb2    = (unsigned short*)(pool + 11534336);
    unsigned short* xb3    = (unsigned short*)(pool + 12582912);
    unsigned short* hist   = (unsigned short*)(pool + 14155776);  // [2][16][256][256] bf16
    // phase C (attention)
    unsigned short* kbf    = (unsigned short*)(pool + 0);         // vT = kbf + 2097152
    unsigned short* vT     = (unsigned short*)(pool + 1048576);
    unsigned short* qbf    = (unsigned short*)(pool + 2097152);
    unsigned short* probs  = (unsigned short*)(pool + 9437184);   // clobbers hist AFTER kv
    unsigned short* dinb   = (unsigned short*)(pool + 16008192);
    unsigned short* ctxb   = (unsigned short*)(pool + 16622592);
    // phase D (decoder)
    unsigned short* gatesb = (unsigned short*)(pool + 0);
    unsigned short* h2b    = (unsigned short*)big;
    unsigned short* h1b    = (unsigned short*)(big + 4000000);
    unsigned short* xcat   = (unsigned short*)(pool + 19899392);
    // weights
    float*          WB     = pool + 23790592;
    unsigned short* cWc  = (unsigned short*)(WB + 0);
    unsigned short* cWif = (unsigned short*)(WB + 1966080);   // cWib contiguous after
    unsigned short* cWib = (unsigned short*)(WB + 2228224);
    unsigned short* cWkv = (unsigned short*)(WB + 2490368);
    unsigned short* cWq  = (unsigned short*)(WB + 2752512);
    unsigned short* cWo  = (unsigned short*)(WB + 2777088);
    unsigned short* cW1  = (unsigned short*)(WB + 2908160);
    unsigned short* cW2  = (unsigned short*)(WB + 3842048);
    unsigned short* cWm  = (unsigned short*)(WB + 5414912);

    auto ceil256 = [](int n) { return (n + 255) / 256; };

    hipMemsetAsync(hstage, 0, 8192 * 8 + 128, stream);

    // ---- fused prologue ----
    cvt_all<<<ceil256(10960896 + B_ * S_ * D_ + B_ * T_ * 96), 256, 0, stream>>>(
        conv_w, Wih_f, Wih_b, Wk, Wv, Wq, Wo, Wih1, Wih2, melW, stopW,
        text, emb, mel_t,
        cWc, cWif, cWib, cWkv, cWq, cWo, cW1, cW2, cWm,
        xb0, dinb, xcat);

    // ---- encoder: 3 convs (implicit GEMM) ----
    {
        dim3 grid(4, 32);
        conv_mfma<<<grid, 256, 0, stream>>>(xb0, cWc,           xb1,
            conv_b, bn_g, bn_b, bn_m, bn_v, zbuf);
        conv_mfma<<<grid, 256, 0, stream>>>(xb1, cWc + 1310720, xb2,
            conv_b + 512, bn_g + 512, bn_b + 512, bn_m + 512, bn_v + 512, zbuf);
        conv_mfma<<<grid, 256, 0, stream>>>(xb2, cWc + 2621440, xb3,
            conv_b + 1024, bn_g + 1024, bn_b + 1024, bn_m + 1024, bn_v + 1024, zbuf);
    }

    // ---- encoder LSTM: ONE merged gi GEMM (N=2048, fwd|bwd), then scan ----
    launch_mfma(stream, xb3, cWif, gibuf, b_f, S_ * B_, 2048, 512, 2048, 6, 1, b_b);
    lstm_persist9<<<4, 1024, 0, stream>>>(gi_f, gi_b, Whh_f, Whh_b, hist, hstage);

    // ---- attention projections (kv reads hist in-place via aperm=2) ----
    launch_mfma(stream, hist, cWkv, kbf, bk, B_ * S_, 1024, 512, 512, 5, 2, bv);
    launch_mfma(stream, dinb, cWq, qbf, bq, B_ * T_, 512, 96, 512, 2);

    // ---- attention: fused QK^T+softmax, then PV ----
    attn_qksm<<<dim3(13, 64), 256, 0, stream>>>(qbf, kbf, probs);
    attn_pv<<<dim3(1, 7, 64), 256, 0, stream>>>(probs, vT, ctxb);

    // ---- Wo projection -> xcat[:, 0:512) bf16 ----
    launch_mfma(stream, ctxb, cWo, xcat, bo, B_ * T_, 512, 512, 608, 2);

    // ---- decoder (bf16 gates; XCD-swizzled GEMMs) ----
    launch_mfma(stream, xcat, cW1, gatesb, nullptr, B_ * T_, 3072, 608, 3072, 2, 0, nullptr, 1);
    dec_cellb2<<<ceil256(B_ * T_ * 512), 256, 0, stream>>>(gatesb, b1, h1b, B_ * T_);
    launch_mfma(stream, h1b, cW2, gatesb, nullptr, B_ * T_, 3072, 1024, 3072, 2, 0, nullptr, 1);
    dec_cellb2<<<ceil256(B_ * T_ * 512), 256, 0, stream>>>(gatesb, b2, h2b, B_ * T_);

    // ---- output heads: mel + stop in ONE GEMM ----
    launch_mfma(stream, h2b, cWm, out, melb, B_ * T_, 128, 1024, 80, 4, 0, stopb);
}